// Round 1
// baseline (726.455 us; speedup 1.0000x reference)
//
#include <hip/hip_runtime.h>
#include <math.h>

#define BLK1 512
#define NEG_INF (-3.402823466e38f)

// ---------------- Kernel 0: fold BN into head weights ----------------
__global__ void fold_kernel(const float* __restrict__ bn_gamma,
                            const float* __restrict__ bn_beta,
                            const float* __restrict__ bn_mean,
                            const float* __restrict__ bn_var,
                            const float* __restrict__ lw,   // (10,512)
                            const float* __restrict__ lb,   // (10)
                            const float* __restrict__ dw,   // (1,512)
                            const float* __restrict__ db,   // (1)
                            float* __restrict__ wf,         // (10,512)
                            float* __restrict__ bf,         // (10)
                            float* __restrict__ dwf,        // (512)
                            float* __restrict__ dbf)        // (1)
{
    __shared__ float sh[512];
    int j = threadIdx.x;
    float s = rsqrtf(bn_var[j] + 1e-5f) * bn_gamma[j];
    float shift = bn_beta[j] - bn_mean[j] * s;
    sh[j] = shift;
#pragma unroll
    for (int c = 0; c < 10; ++c) wf[c * 512 + j] = lw[c * 512 + j] * s;
    dwf[j] = dw[j] * s;
    __syncthreads();
    if (j < 10) {
        float acc = lb[j];
        for (int q = 0; q < 512; ++q) acc += sh[q] * lw[j * 512 + q];
        bf[j] = acc;
    } else if (j == 10) {
        float acc = db[0];
        for (int q = 0; q < 512; ++q) acc += sh[q] * dw[q];
        dbf[0] = acc;
    }
}

// ---------------- Kernel 1: conv + cummax ----------------
// Block = (b, scale, group of 8 h). 512 threads. x[b] staged in LDS with
// 20-wide zero halo each side. Thread owns t = tid + 512*r, r=0..3
// (stride-4B LDS reads -> conflict-free; 1 read feeds 8 h FMAs).
template <int K>
__device__ __forceinline__ void conv_body(const float* __restrict__ x,
                                          const float* __restrict__ w,
                                          const float* __restrict__ bias,
                                          float* __restrict__ feat,
                                          float* xs, int b, int g, int scale)
{
    const int tid = threadIdx.x;
    constexpr int P = K / 2;

    // stage padded x[b]: xs[c*2088 + i] = x[b][c][i-20], zero outside
    for (int idx = tid; idx < 13 * 2088; idx += BLK1) {
        int c = idx / 2088;
        int i = idx - c * 2088;
        int t = i - 20;
        xs[idx] = (t >= 0 && t < 2048) ? x[(b * 13 + c) * 2048 + t] : 0.f;
    }
    __syncthreads();

    const int h0 = g * 8;
    float acc[8][4];
#pragma unroll
    for (int h = 0; h < 8; ++h) {
        float bv = bias[h0 + h];
#pragma unroll
        for (int r = 0; r < 4; ++r) acc[h][r] = bv;
    }

    for (int c = 0; c < 13; ++c) {
        const float* xrow = xs + c * 2088 + (20 - P) + tid;
#pragma unroll 2
        for (int k = 0; k < K; ++k) {
            float wv[8];
#pragma unroll
            for (int h = 0; h < 8; ++h) wv[h] = w[((h0 + h) * 13 + c) * K + k];
            float xv0 = xrow[k];
            float xv1 = xrow[k + 512];
            float xv2 = xrow[k + 1024];
            float xv3 = xrow[k + 1536];
#pragma unroll
            for (int h = 0; h < 8; ++h) {
                acc[h][0] = fmaf(xv0, wv[h], acc[h][0]);
                acc[h][1] = fmaf(xv1, wv[h], acc[h][1]);
                acc[h][2] = fmaf(xv2, wv[h], acc[h][2]);
                acc[h][3] = fmaf(xv3, wv[h], acc[h][3]);
            }
        }
    }
    __syncthreads();  // done reading xs as x-buffer; reuse as scan scratch

    float* ft = xs;        // [2048]
    float* sc = xs + 2048; // [BLK1]
    for (int h = 0; h < 8; ++h) {
#pragma unroll
        for (int r = 0; r < 4; ++r) ft[tid + BLK1 * r] = acc[h][r];
        __syncthreads();
        int base = tid * 4;
        float v0 = ft[base], v1 = ft[base + 1], v2 = ft[base + 2], v3 = ft[base + 3];
        v1 = fmaxf(v1, v0);
        v2 = fmaxf(v2, v1);
        v3 = fmaxf(v3, v2);
        sc[tid] = v3;
        __syncthreads();
        // Hillis-Steele inclusive max-scan over 512 thread partials
        for (int off = 1; off < BLK1; off <<= 1) {
            float o = (tid >= off) ? sc[tid - off] : NEG_INF;
            float cur = sc[tid];
            __syncthreads();
            sc[tid] = fmaxf(cur, o);
            __syncthreads();
        }
        float pre = (tid > 0) ? sc[tid - 1] : NEG_INF;
        float4 out;
        out.x = fmaxf(v0, pre);
        out.y = fmaxf(v1, pre);
        out.z = fmaxf(v2, pre);
        out.w = fmaxf(v3, pre);
        *(float4*)(feat + ((size_t)(b * 512 + scale * 128 + h0 + h)) * 2048 + base) = out;
        __syncthreads();  // protect sc/ft before next h overwrites
    }
}

__global__ __launch_bounds__(BLK1) void conv_cummax_kernel(
    const float* __restrict__ x,
    const float* __restrict__ w1, const float* __restrict__ b1,
    const float* __restrict__ w2, const float* __restrict__ b2,
    const float* __restrict__ w3, const float* __restrict__ b3,
    const float* __restrict__ w4, const float* __restrict__ b4,
    float* __restrict__ feat)
{
    __shared__ float xs[13 * 2088];
    int scale = blockIdx.x & 3;
    int g = (blockIdx.x >> 2) & 15;
    int b = blockIdx.x >> 6;
    if (scale == 0)      conv_body<10>(x, w1, b1, feat, xs, b, g, 0);
    else if (scale == 1) conv_body<20>(x, w2, b2, feat, xs, b, g, 1);
    else if (scale == 2) conv_body<30>(x, w3, b3, feat, xs, b, g, 2);
    else                 conv_body<40>(x, w4, b4, feat, xs, b, g, 3);
}

// ---------------- Kernel 2: head (logits softmax + delta raw) ----------------
__global__ __launch_bounds__(256) void head_kernel(
    const float* __restrict__ feat, const float* __restrict__ wf,
    const float* __restrict__ bf, const float* __restrict__ dwf,
    const float* __restrict__ dbf, float* __restrict__ probs,
    float* __restrict__ delta_raw)
{
    int b = blockIdx.x >> 3;
    int t = ((blockIdx.x & 7) << 8) + threadIdx.x;
    float acc[10];
#pragma unroll
    for (int c = 0; c < 10; ++c) acc[c] = bf[c];
    float accd = dbf[0];
    const float* fb = feat + (size_t)b * 512 * 2048 + t;
#pragma unroll 4
    for (int j = 0; j < 512; ++j) {
        float v = fb[(size_t)j * 2048];
#pragma unroll
        for (int c = 0; c < 10; ++c) acc[c] = fmaf(v, wf[c * 512 + j], acc[c]);
        accd = fmaf(v, dwf[j], accd);
    }
    float m = acc[0];
#pragma unroll
    for (int c = 1; c < 10; ++c) m = fmaxf(m, acc[c]);
    float s = 0.f;
    float e[10];
#pragma unroll
    for (int c = 0; c < 10; ++c) {
        e[c] = __expf(acc[c] - m);
        s += e[c];
    }
    float inv = 1.f / s;
    float* po = probs + ((size_t)(b * 2048 + t)) * 10;
#pragma unroll
    for (int c = 0; c < 10; ++c) po[c] = e[c] * inv;
    delta_raw[b * 2048 + t] = accd;
}

// ---------------- Kernel 3: softmax over T + budget chain ----------------
__global__ __launch_bounds__(256) void budget_kernel(
    const float* __restrict__ delta_raw, float* __restrict__ pts)
{
    __shared__ float ds[2048];
    __shared__ float sc[256];
    int b = blockIdx.x;
    int tid = threadIdx.x;
    const float* row = delta_raw + b * 2048;
    int base = tid * 8;
    float d[8];
#pragma unroll
    for (int i = 0; i < 8; ++i) d[i] = row[base + i];
    float m = d[0];
#pragma unroll
    for (int i = 1; i < 8; ++i) m = fmaxf(m, d[i]);
    sc[tid] = m;
    __syncthreads();
    for (int off = 128; off > 0; off >>= 1) {
        if (tid < off) sc[tid] = fmaxf(sc[tid], sc[tid + off]);
        __syncthreads();
    }
    m = sc[0];
    __syncthreads();
    float s = 0.f;
#pragma unroll
    for (int i = 0; i < 8; ++i) {
        d[i] = __expf(d[i] - m);
        s += d[i];
    }
    sc[tid] = s;
    __syncthreads();
    for (int off = 128; off > 0; off >>= 1) {
        if (tid < off) sc[tid] += sc[tid + off];
        __syncthreads();
    }
    float inv = 1.f / sc[0];
    __syncthreads();
#pragma unroll
    for (int i = 0; i < 8; ++i) {
        d[i] *= inv;
        ds[base + i] = d[i];
    }
    // budget[t] = prod_{s=1..t}(1-delta[s]); g[0]=1
    float g[8], p = 1.f;
#pragma unroll
    for (int i = 0; i < 8; ++i) {
        int t = base + i;
        float gv = (t == 0) ? 1.f : (1.f - d[i]);
        p *= gv;
        g[i] = p;
    }
    sc[tid] = p;
    __syncthreads();
    for (int off = 1; off < 256; off <<= 1) {
        float o = (tid >= off) ? sc[tid - off] : 1.f;
        float cur = sc[tid];
        __syncthreads();
        sc[tid] = cur * o;
        __syncthreads();
    }
    float pre = (tid > 0) ? sc[tid - 1] : 1.f;
    __syncthreads();
#pragma unroll
    for (int i = 0; i < 8; ++i) {
        int t = base + i;
        float budget = pre * g[i];
        float pt = (t < 2047) ? ds[t + 1] * budget : budget;
        pts[b * 2048 + t] = pt;
    }
}

extern "C" void kernel_launch(void* const* d_in, const int* in_sizes, int n_in,
                              void* d_out, int out_size, void* d_ws, size_t ws_size,
                              hipStream_t stream)
{
    const float* x     = (const float*)d_in[0];
    const float* w1    = (const float*)d_in[1];
    const float* b1    = (const float*)d_in[2];
    const float* w2    = (const float*)d_in[3];
    const float* b2    = (const float*)d_in[4];
    const float* w3    = (const float*)d_in[5];
    const float* b3    = (const float*)d_in[6];
    const float* w4    = (const float*)d_in[7];
    const float* b4    = (const float*)d_in[8];
    const float* gamma = (const float*)d_in[9];
    const float* beta  = (const float*)d_in[10];
    const float* mean  = (const float*)d_in[11];
    const float* var   = (const float*)d_in[12];
    const float* lw    = (const float*)d_in[13];
    const float* lb    = (const float*)d_in[14];
    const float* dw    = (const float*)d_in[15];
    const float* db    = (const float*)d_in[16];

    float* ws   = (float*)d_ws;
    float* feat = ws;                              // 32*512*2048 = 33554432
    float* draw = ws + (size_t)32 * 512 * 2048;    // 65536
    float* wf   = draw + 65536;                    // 5120
    float* dwf  = wf + 5120;                       // 512
    float* bf   = dwf + 512;                       // 10
    float* dbf  = bf + 10;                         // 1

    float* probs = (float*)d_out;
    float* pts   = probs + (size_t)32 * 2048 * 10;

    hipLaunchKernelGGL(fold_kernel, dim3(1), dim3(512), 0, stream,
                       gamma, beta, mean, var, lw, lb, dw, db, wf, bf, dwf, dbf);
    hipLaunchKernelGGL(conv_cummax_kernel, dim3(2048), dim3(BLK1), 0, stream,
                       x, w1, b1, w2, b2, w3, b3, w4, b4, feat);
    hipLaunchKernelGGL(head_kernel, dim3(256), dim3(256), 0, stream,
                       feat, wf, bf, dwf, dbf, probs, draw);
    hipLaunchKernelGGL(budget_kernel, dim3(32), dim3(256), 0, stream, draw, pts);
}

// Round 2
// 515.212 us; speedup vs baseline: 1.4100x; 1.4100x over previous
//
#include <hip/hip_runtime.h>
#include <math.h>

#define BLK1 512
#define NEG_INF (-3.402823466e38f)

// ---------------- Kernel 0: fold BN into head weights ----------------
__global__ void fold_kernel(const float* __restrict__ bn_gamma,
                            const float* __restrict__ bn_beta,
                            const float* __restrict__ bn_mean,
                            const float* __restrict__ bn_var,
                            const float* __restrict__ lw,   // (10,512)
                            const float* __restrict__ lb,   // (10)
                            const float* __restrict__ dw,   // (1,512)
                            const float* __restrict__ db,   // (1)
                            float* __restrict__ wf,         // (10,512)
                            float* __restrict__ bf,         // (10)
                            float* __restrict__ dwf,        // (512)
                            float* __restrict__ dbf)        // (1)
{
    __shared__ float sh[512];
    int j = threadIdx.x;
    float s = rsqrtf(bn_var[j] + 1e-5f) * bn_gamma[j];
    float shift = bn_beta[j] - bn_mean[j] * s;
    sh[j] = shift;
#pragma unroll
    for (int c = 0; c < 10; ++c) wf[c * 512 + j] = lw[c * 512 + j] * s;
    dwf[j] = dw[j] * s;
    __syncthreads();
    if (j < 10) {
        float acc = lb[j];
        for (int q = 0; q < 512; ++q) acc += sh[q] * lw[j * 512 + q];
        bf[j] = acc;
    } else if (j == 10) {
        float acc = db[0];
        for (int q = 0; q < 512; ++q) acc += sh[q] * dw[q];
        dbf[0] = acc;
    }
}

// ---------------- Kernel 1: conv + cummax ----------------
// Block = (b, scale, group of 8 h). 512 threads. Channel-split staging:
// 7 then 6 channels of x[b] in LDS (59 KB -> 2 blocks/CU). Thread owns
// t = tid + 512*r, r=0..3 (stride-1 LDS reads, conflict-free).
// Cummax via wave shfl scans + one barrier (vs ~160 barriers before).
template <int K>
__device__ __forceinline__ void conv_body(const float* __restrict__ x,
                                          const float* __restrict__ w,
                                          const float* __restrict__ bias,
                                          float* __restrict__ feat,
                                          float* xs, float (*part)[4][8],
                                          int b, int g, int scale)
{
    const int tid = threadIdx.x;
    constexpr int P = K / 2;
    const int h0 = g * 8;

    float acc[8][4];
#pragma unroll
    for (int h = 0; h < 8; ++h) {
        float bv = bias[h0 + h];
#pragma unroll
        for (int r = 0; r < 4; ++r) acc[h][r] = bv;
    }

#pragma unroll 1
    for (int phase = 0; phase < 2; ++phase) {
        const int c0 = phase ? 7 : 0;
        const int c1 = phase ? 13 : 7;
        if (phase) __syncthreads();   // WAR: previous accumulate done reading xs
        // stage channels [c0, c1) with 20-wide zero halo each side
        for (int c = c0; c < c1; ++c) {
            const float* src = x + ((size_t)(b * 13 + c)) * 2048;
            float* dst = xs + (c - c0) * 2088;
#pragma unroll 1
            for (int i = tid; i < 2088; i += BLK1) {
                int t = i - 20;
                dst[i] = (t >= 0 && t < 2048) ? src[t] : 0.f;
            }
        }
        __syncthreads();
#pragma unroll 1
        for (int c = c0; c < c1; ++c) {
            const float* xrow = xs + (c - c0) * 2088 + (20 - P) + tid;
            const float* wc = w + ((size_t)(h0 * 13 + c)) * K;  // + h*13*K + k
#pragma unroll 2
            for (int k = 0; k < K; ++k) {
                float wv[8];
#pragma unroll
                for (int h = 0; h < 8; ++h) wv[h] = wc[h * 13 * K + k];
                float xv0 = xrow[k];
                float xv1 = xrow[k + 512];
                float xv2 = xrow[k + 1024];
                float xv3 = xrow[k + 1536];
#pragma unroll
                for (int h = 0; h < 8; ++h) {
                    acc[h][0] = fmaf(xv0, wv[h], acc[h][0]);
                    acc[h][1] = fmaf(xv1, wv[h], acc[h][1]);
                    acc[h][2] = fmaf(xv2, wv[h], acc[h][2]);
                    acc[h][3] = fmaf(xv3, wv[h], acc[h][3]);
                }
            }
        }
    }

    // ---- cummax: per r-segment wave scans, then compose with one barrier ----
    const int wid = tid >> 6;
    const int lane = tid & 63;
#pragma unroll
    for (int h = 0; h < 8; ++h) {
#pragma unroll
        for (int r = 0; r < 4; ++r) {
            float s = acc[h][r];
#pragma unroll
            for (int off = 1; off < 64; off <<= 1) {
                float o = __shfl_up(s, off);
                if (lane >= off) s = fmaxf(s, o);
            }
            acc[h][r] = s;                       // inclusive scan within wave
            if (lane == 63) part[h][r][wid] = s; // wave total
        }
    }
    __syncthreads();

#pragma unroll
    for (int h = 0; h < 8; ++h) {
        float* fh = feat + ((size_t)(b * 512 + scale * 128 + h0 + h)) * 2048;
        float carry = NEG_INF;  // max over all totals of segments r' < r
#pragma unroll
        for (int r = 0; r < 4; ++r) {
            float off_v = carry;
            float tot = NEG_INF;
#pragma unroll
            for (int wv = 0; wv < 8; ++wv) {
                float pv = part[h][r][wv];
                if (wv < wid) off_v = fmaxf(off_v, pv);
                tot = fmaxf(tot, pv);
            }
            fh[tid + 512 * r] = fmaxf(acc[h][r], off_v);
            carry = fmaxf(carry, tot);
        }
    }
}

__global__ __launch_bounds__(BLK1, 4) void conv_cummax_kernel(
    const float* __restrict__ x,
    const float* __restrict__ w1, const float* __restrict__ b1,
    const float* __restrict__ w2, const float* __restrict__ b2,
    const float* __restrict__ w3, const float* __restrict__ b3,
    const float* __restrict__ w4, const float* __restrict__ b4,
    float* __restrict__ feat)
{
    __shared__ float xs[7 * 2088];
    __shared__ float part[8][4][8];
    int scale = blockIdx.x & 3;
    int g = (blockIdx.x >> 2) & 15;
    int b = blockIdx.x >> 6;
    if (scale == 0)      conv_body<10>(x, w1, b1, feat, xs, part, b, g, 0);
    else if (scale == 1) conv_body<20>(x, w2, b2, feat, xs, part, b, g, 1);
    else if (scale == 2) conv_body<30>(x, w3, b3, feat, xs, part, b, g, 2);
    else                 conv_body<40>(x, w4, b4, feat, xs, part, b, g, 3);
}

// ---------------- Kernel 2: head (logits softmax + delta raw) ----------------
__global__ __launch_bounds__(256) void head_kernel(
    const float* __restrict__ feat, const float* __restrict__ wf,
    const float* __restrict__ bf, const float* __restrict__ dwf,
    const float* __restrict__ dbf, float* __restrict__ probs,
    float* __restrict__ delta_raw)
{
    int b = blockIdx.x >> 3;
    int t = ((blockIdx.x & 7) << 8) + threadIdx.x;
    float acc[10];
#pragma unroll
    for (int c = 0; c < 10; ++c) acc[c] = bf[c];
    float accd = dbf[0];
    const float* fb = feat + (size_t)b * 512 * 2048 + t;
#pragma unroll 4
    for (int j = 0; j < 512; ++j) {
        float v = fb[(size_t)j * 2048];
#pragma unroll
        for (int c = 0; c < 10; ++c) acc[c] = fmaf(v, wf[c * 512 + j], acc[c]);
        accd = fmaf(v, dwf[j], accd);
    }
    float m = acc[0];
#pragma unroll
    for (int c = 1; c < 10; ++c) m = fmaxf(m, acc[c]);
    float s = 0.f;
    float e[10];
#pragma unroll
    for (int c = 0; c < 10; ++c) {
        e[c] = __expf(acc[c] - m);
        s += e[c];
    }
    float inv = 1.f / s;
    float* po = probs + ((size_t)(b * 2048 + t)) * 10;
#pragma unroll
    for (int c = 0; c < 10; ++c) po[c] = e[c] * inv;
    delta_raw[b * 2048 + t] = accd;
}

// ---------------- Kernel 3: softmax over T + budget chain ----------------
__global__ __launch_bounds__(256) void budget_kernel(
    const float* __restrict__ delta_raw, float* __restrict__ pts)
{
    __shared__ float ds[2048];
    __shared__ float sc[256];
    int b = blockIdx.x;
    int tid = threadIdx.x;
    const float* row = delta_raw + b * 2048;
    int base = tid * 8;
    float d[8];
#pragma unroll
    for (int i = 0; i < 8; ++i) d[i] = row[base + i];
    float m = d[0];
#pragma unroll
    for (int i = 1; i < 8; ++i) m = fmaxf(m, d[i]);
    sc[tid] = m;
    __syncthreads();
    for (int off = 128; off > 0; off >>= 1) {
        if (tid < off) sc[tid] = fmaxf(sc[tid], sc[tid + off]);
        __syncthreads();
    }
    m = sc[0];
    __syncthreads();
    float s = 0.f;
#pragma unroll
    for (int i = 0; i < 8; ++i) {
        d[i] = __expf(d[i] - m);
        s += d[i];
    }
    sc[tid] = s;
    __syncthreads();
    for (int off = 128; off > 0; off >>= 1) {
        if (tid < off) sc[tid] += sc[tid + off];
        __syncthreads();
    }
    float inv = 1.f / sc[0];
    __syncthreads();
#pragma unroll
    for (int i = 0; i < 8; ++i) {
        d[i] *= inv;
        ds[base + i] = d[i];
    }
    // budget[t] = prod_{s=1..t}(1-delta[s]); g[0]=1
    float g[8], p = 1.f;
#pragma unroll
    for (int i = 0; i < 8; ++i) {
        int t = base + i;
        float gv = (t == 0) ? 1.f : (1.f - d[i]);
        p *= gv;
        g[i] = p;
    }
    sc[tid] = p;
    __syncthreads();
    for (int off = 1; off < 256; off <<= 1) {
        float o = (tid >= off) ? sc[tid - off] : 1.f;
        float cur = sc[tid];
        __syncthreads();
        sc[tid] = cur * o;
        __syncthreads();
    }
    float pre = (tid > 0) ? sc[tid - 1] : 1.f;
    __syncthreads();
#pragma unroll
    for (int i = 0; i < 8; ++i) {
        int t = base + i;
        float budget = pre * g[i];
        float pt = (t < 2047) ? ds[t + 1] * budget : budget;
        pts[b * 2048 + t] = pt;
    }
}

extern "C" void kernel_launch(void* const* d_in, const int* in_sizes, int n_in,
                              void* d_out, int out_size, void* d_ws, size_t ws_size,
                              hipStream_t stream)
{
    const float* x     = (const float*)d_in[0];
    const float* w1    = (const float*)d_in[1];
    const float* b1    = (const float*)d_in[2];
    const float* w2    = (const float*)d_in[3];
    const float* b2    = (const float*)d_in[4];
    const float* w3    = (const float*)d_in[5];
    const float* b3    = (const float*)d_in[6];
    const float* w4    = (const float*)d_in[7];
    const float* b4    = (const float*)d_in[8];
    const float* gamma = (const float*)d_in[9];
    const float* beta  = (const float*)d_in[10];
    const float* mean  = (const float*)d_in[11];
    const float* var   = (const float*)d_in[12];
    const float* lw    = (const float*)d_in[13];
    const float* lb    = (const float*)d_in[14];
    const float* dw    = (const float*)d_in[15];
    const float* db    = (const float*)d_in[16];

    float* ws   = (float*)d_ws;
    float* feat = ws;                              // 32*512*2048
    float* draw = ws + (size_t)32 * 512 * 2048;    // 65536
    float* wf   = draw + 65536;                    // 5120
    float* dwf  = wf + 5120;                       // 512
    float* bf   = dwf + 512;                       // 10
    float* dbf  = bf + 10;                         // 1

    float* probs = (float*)d_out;
    float* pts   = probs + (size_t)32 * 2048 * 10;

    hipLaunchKernelGGL(fold_kernel, dim3(1), dim3(512), 0, stream,
                       gamma, beta, mean, var, lw, lb, dw, db, wf, bf, dwf, dbf);
    hipLaunchKernelGGL(conv_cummax_kernel, dim3(2048), dim3(BLK1), 0, stream,
                       x, w1, b1, w2, b2, w3, b3, w4, b4, feat);
    hipLaunchKernelGGL(head_kernel, dim3(256), dim3(256), 0, stream,
                       feat, wf, bf, dwf, dbf, probs, draw);
    hipLaunchKernelGGL(budget_kernel, dim3(32), dim3(256), 0, stream, draw, pts);
}

// Round 3
// 205.086 us; speedup vs baseline: 3.5422x; 2.5122x over previous
//
#include <hip/hip_runtime.h>
#include <math.h>

#define NEG_INF (-3.402823466e38f)

typedef float f32x4 __attribute__((ext_vector_type(4)));
typedef short bf16x8 __attribute__((ext_vector_type(8)));

__device__ __forceinline__ unsigned short f2bf(float f) {
    unsigned int u = __float_as_uint(f);
    unsigned int r = (u + 0x7FFFu + ((u >> 16) & 1u)) >> 16;
    return (unsigned short)r;
}
__device__ __forceinline__ float bf2f(unsigned short s) {
    return __uint_as_float(((unsigned int)s) << 16);
}
// LDS XOR swizzle on byte address (rows are 32B): spreads stride-32B lane
// patterns across bank quads; bijective within 128B groups, applied on both
// write (staging) and read (A-frags).
__device__ __forceinline__ int swz(int a) { return a ^ (((a >> 5) & 7) << 4); }

// ---------------- fold BN into head weights ----------------
__global__ void fold_kernel(const float* __restrict__ bn_gamma,
                            const float* __restrict__ bn_beta,
                            const float* __restrict__ bn_mean,
                            const float* __restrict__ bn_var,
                            const float* __restrict__ lw, const float* __restrict__ lb,
                            const float* __restrict__ dw, const float* __restrict__ db,
                            float* __restrict__ wf, float* __restrict__ bf,
                            float* __restrict__ dwf, float* __restrict__ dbf)
{
    __shared__ float sh[512];
    int j = threadIdx.x;
    float s = rsqrtf(bn_var[j] + 1e-5f) * bn_gamma[j];
    float shift = bn_beta[j] - bn_mean[j] * s;
    sh[j] = shift;
#pragma unroll
    for (int c = 0; c < 10; ++c) wf[c * 512 + j] = lw[c * 512 + j] * s;
    dwf[j] = dw[j] * s;
    __syncthreads();
    if (j < 10) {
        float acc = lb[j];
        for (int q = 0; q < 512; ++q) acc += sh[q] * lw[j * 512 + q];
        bf[j] = acc;
    } else if (j == 10) {
        float acc = db[0];
        for (int q = 0; q < 512; ++q) acc += sh[q] * dw[q];
        dbf[0] = acc;
    }
}

// ---------------- prep: x -> xT bf16 [b][2176 rows][16c], row r = t' + 20 ----
__global__ void xt_prep(const float* __restrict__ x, unsigned short* __restrict__ xT)
{
    int idx = blockIdx.x * 256 + threadIdx.x;   // b*2176 + r
    if (idx >= 32 * 2176) return;
    int b = idx / 2176, r = idx - b * 2176;
    int t = r - 20;
    unsigned short row[16];
#pragma unroll
    for (int c = 0; c < 16; ++c) {
        float v = (c < 13 && t >= 0 && t < 2048) ? x[((size_t)(b * 13 + c)) * 2048 + t] : 0.f;
        row[c] = f2bf(v);
    }
    uint4* dst = (uint4*)(xT + (size_t)idx * 16);
    uint4 v0, v1;
    v0.x = row[0] | ((unsigned)row[1] << 16);  v0.y = row[2] | ((unsigned)row[3] << 16);
    v0.z = row[4] | ((unsigned)row[5] << 16);  v0.w = row[6] | ((unsigned)row[7] << 16);
    v1.x = row[8] | ((unsigned)row[9] << 16);  v1.y = row[10] | ((unsigned)row[11] << 16);
    v1.z = row[12] | ((unsigned)row[13] << 16); v1.w = row[14] | ((unsigned)row[15] << 16);
    dst[0] = v0; dst[1] = v1;
}

// ---------------- prep: weights -> MFMA B-fragments (bf16, lane layout) ----
// frag layout: [scale][ht(8)][k0(Kc/2)] x [lane 64][j 8]
// B[kdim][n]: n = lane&15 (h), kdim = 8*(lane>>4)+j; c = 8*((lane>>4)&1)+j, dk = lane>>5
__global__ void bfrag_prep(const float* __restrict__ w1, const float* __restrict__ w2,
                           const float* __restrict__ w3, const float* __restrict__ w4,
                           unsigned short* __restrict__ Bfrag)
{
    int idx = blockIdx.x * 256 + threadIdx.x;   // frag*64 + lane
    if (idx >= 400 * 64) return;
    int lane = idx & 63, frag = idx >> 6;
    int rel, Kc; const float* w;
    if (frag < 40)       { rel = frag;       w = w1; Kc = 10; }
    else if (frag < 120) { rel = frag - 40;  w = w2; Kc = 20; }
    else if (frag < 240) { rel = frag - 120; w = w3; Kc = 30; }
    else                 { rel = frag - 240; w = w4; Kc = 40; }
    int kh = Kc / 2;
    int ht = rel / kh;
    int k0 = rel - ht * kh;
    int h = ht * 16 + (lane & 15);
    int dk = lane >> 5;
    int cbase = 8 * ((lane >> 4) & 1);
    int k = 2 * k0 + dk;
    unsigned short e[8];
#pragma unroll
    for (int j = 0; j < 8; ++j) {
        int c = cbase + j;
        float v = (c < 13) ? w[((size_t)h * 13 + c) * Kc + k] : 0.f;
        e[j] = f2bf(v);
    }
    uint4 pk;
    pk.x = e[0] | ((unsigned)e[1] << 16); pk.y = e[2] | ((unsigned)e[3] << 16);
    pk.z = e[4] | ((unsigned)e[5] << 16); pk.w = e[6] | ((unsigned)e[7] << 16);
    *(uint4*)(Bfrag + (size_t)frag * 512 + lane * 8) = pk;
}

// ---------------- conv via MFMA + local cummax ----------------
// grid: 256 = (b 32) x (scale 4) x (tq 2). block 512 = 8 waves = 2 hgrp x 4 twq.
// wave: 4 h-tiles(16h) x 16 t-tiles(16t); per k0: 4 ds_read_b128 (A) +
// 4 global B-frag loads + 16 MFMA. Local cummax over wave's 256-t range;
// cross-range composition deferred to head via totals[].
__global__ __launch_bounds__(512, 4) void conv_mfma(
    const unsigned short* __restrict__ xT, const unsigned short* __restrict__ Bfrag,
    const float* __restrict__ b1, const float* __restrict__ b2,
    const float* __restrict__ b3, const float* __restrict__ b4,
    unsigned short* __restrict__ feat, float* __restrict__ totals)
{
    __shared__ __align__(16) unsigned short xs[1088 * 16];
    const int tid = threadIdx.x;
    const int b = blockIdx.x >> 3;
    const int scale = (blockIdx.x >> 1) & 3;
    const int tq = blockIdx.x & 1;
    const int kh_tab[4] = {5, 10, 15, 20};
    const int so_tab[4] = {0, 40, 120, 240};
    const int KH = kh_tab[scale];
    const int P = 5 * (scale + 1);
    const float* bias = (scale == 0) ? b1 : (scale == 1) ? b2 : (scale == 2) ? b3 : b4;

    // stage rows [r0, r0+1088) of xT[b] into LDS (swizzled)
    int r0 = 20 + tq * 1024 - P;
    const unsigned short* src = xT + ((size_t)b * 2176 + r0) * 16;
#pragma unroll
    for (int it = 0; it < 5; ++it) {
        int chunk = it * 512 + tid;
        if (chunk < 2176) {
            uint4 v = *(const uint4*)(src + chunk * 8);
            *(uint4*)((char*)xs + swz(chunk * 16)) = v;
        }
    }
    __syncthreads();

    const int lane = tid & 63;
    const int wave = tid >> 6;
    const int hgrp = wave & 1;
    const int twq = wave >> 1;
    const int rq = tq * 4 + twq;

    const unsigned short* bfr = Bfrag + (size_t)(so_tab[scale] + hgrp * 4 * KH) * 512 + lane * 8;
    float bv[4];
#pragma unroll
    for (int ht = 0; ht < 4; ++ht) bv[ht] = bias[hgrp * 64 + ht * 16 + (lane & 15)];

    // A byte address (pre-swizzle): row = twq*256 + (lane&15) + dk(lane>>5); half = (lane>>4)&1
    int abase = ((twq * 256) + (lane & 15) + (lane >> 5)) * 32 + ((lane >> 4) & 1) * 16;

    float carry[4] = {NEG_INF, NEG_INF, NEG_INF, NEG_INF};

#pragma unroll 1
    for (int tg = 0; tg < 4; ++tg) {
        f32x4 acc[4][4];
#pragma unroll
        for (int ht = 0; ht < 4; ++ht)
#pragma unroll
            for (int tt = 0; tt < 4; ++tt)
                acc[ht][tt] = (f32x4){bv[ht], bv[ht], bv[ht], bv[ht]};

#pragma unroll 1
        for (int k0 = 0; k0 < KH; ++k0) {
            bf16x8 B[4];
#pragma unroll
            for (int ht = 0; ht < 4; ++ht)
                B[ht] = *(const bf16x8*)(bfr + (size_t)(ht * KH + k0) * 512);
            int aoff = abase + tg * 2048 + k0 * 64;
            bf16x8 A[4];
#pragma unroll
            for (int tt = 0; tt < 4; ++tt)
                A[tt] = *(const bf16x8*)((const char*)xs + swz(aoff + tt * 512));
#pragma unroll
            for (int ht = 0; ht < 4; ++ht)
#pragma unroll
                for (int tt = 0; tt < 4; ++tt)
                    acc[ht][tt] = __builtin_amdgcn_mfma_f32_16x16x32_bf16(A[tt], B[ht], acc[ht][tt], 0, 0, 0);
        }

        // cummax scan over this tgroup's 4 t-tiles (t order: tt, then rows)
#pragma unroll
        for (int tt = 0; tt < 4; ++tt) {
#pragma unroll
            for (int ht = 0; ht < 4; ++ht) {
                f32x4 v = acc[ht][tt];
                float s0 = v.x;
                float s1 = fmaxf(v.y, s0);
                float s2 = fmaxf(v.z, s1);
                float s3 = fmaxf(v.w, s2);
                float inc = s3;
                float o = __shfl_up(inc, 16); if (lane >= 16) inc = fmaxf(inc, o);
                o = __shfl_up(inc, 32);       if (lane >= 32) inc = fmaxf(inc, o);
                float pre = __shfl_up(inc, 16);
                float base = (lane >= 16) ? fmaxf(carry[ht], pre) : carry[ht];
                s0 = fmaxf(s0, base); s1 = fmaxf(s1, base);
                s2 = fmaxf(s2, base); s3 = fmaxf(s3, base);
                float tot = __shfl(inc, (lane & 15) + 48);
                carry[ht] = fmaxf(carry[ht], tot);
                unsigned int p0 = f2bf(s0) | ((unsigned int)f2bf(s1) << 16);
                unsigned int p1 = f2bf(s2) | ((unsigned int)f2bf(s3) << 16);
                int h = scale * 128 + hgrp * 64 + ht * 16 + (lane & 15);
                int tglob = tq * 1024 + twq * 256 + tg * 64 + tt * 16 + 4 * (lane >> 4);
                uint2 pk; pk.x = p0; pk.y = p1;
                *(uint2*)(feat + ((size_t)(b * 512 + h)) * 2048 + tglob) = pk;
            }
        }
    }
    if (lane < 16) {
#pragma unroll
        for (int ht = 0; ht < 4; ++ht) {
            int j = scale * 128 + hgrp * 64 + ht * 16 + lane;
            totals[((size_t)b * 512 + j) * 8 + rq] = carry[ht];
        }
    }
}

// ---------------- prefix-max over the 8 t-ranges per (b,j) ----------------
__global__ void prefix_kernel(const float* __restrict__ totals, float* __restrict__ prefix)
{
    int idx = blockIdx.x * 256 + threadIdx.x;
    if (idx >= 32 * 512) return;
    float run = NEG_INF;
#pragma unroll
    for (int q = 0; q < 8; ++q) {
        prefix[(size_t)idx * 8 + q] = run;
        run = fmaxf(run, totals[(size_t)idx * 8 + q]);
    }
}

// ---------------- head: prefix fixup + logits softmax + delta raw ----------
__global__ __launch_bounds__(256) void head_kernel(
    const unsigned short* __restrict__ feat, const float* __restrict__ prefix,
    const float* __restrict__ wf, const float* __restrict__ bf,
    const float* __restrict__ dwf, const float* __restrict__ dbf,
    float* __restrict__ probs, float* __restrict__ delta_raw)
{
    int b = blockIdx.x >> 3;
    int tc = blockIdx.x & 7;                  // 256-t chunk == range q
    int t = tc * 256 + threadIdx.x;
    float acc[10];
#pragma unroll
    for (int c = 0; c < 10; ++c) acc[c] = bf[c];
    float accd = dbf[0];
    const unsigned short* fb = feat + (size_t)b * 512 * 2048 + t;
    const float* pf = prefix + ((size_t)b * 512) * 8 + tc;
#pragma unroll 4
    for (int j = 0; j < 512; ++j) {
        float v = fmaxf(bf2f(fb[(size_t)j * 2048]), pf[(size_t)j * 8]);
#pragma unroll
        for (int c = 0; c < 10; ++c) acc[c] = fmaf(v, wf[c * 512 + j], acc[c]);
        accd = fmaf(v, dwf[j], accd);
    }
    float m = acc[0];
#pragma unroll
    for (int c = 1; c < 10; ++c) m = fmaxf(m, acc[c]);
    float s = 0.f;
    float e[10];
#pragma unroll
    for (int c = 0; c < 10; ++c) { e[c] = __expf(acc[c] - m); s += e[c]; }
    float inv = 1.f / s;
    float* po = probs + ((size_t)(b * 2048 + t)) * 10;
#pragma unroll
    for (int c = 0; c < 10; ++c) po[c] = e[c] * inv;
    delta_raw[b * 2048 + t] = accd;
}

// ---------------- softmax over T + budget chain ----------------
__global__ __launch_bounds__(256) void budget_kernel(
    const float* __restrict__ delta_raw, float* __restrict__ pts)
{
    __shared__ float ds[2048];
    __shared__ float sc[256];
    int b = blockIdx.x;
    int tid = threadIdx.x;
    const float* row = delta_raw + b * 2048;
    int base = tid * 8;
    float d[8];
#pragma unroll
    for (int i = 0; i < 8; ++i) d[i] = row[base + i];
    float m = d[0];
#pragma unroll
    for (int i = 1; i < 8; ++i) m = fmaxf(m, d[i]);
    sc[tid] = m;
    __syncthreads();
    for (int off = 128; off > 0; off >>= 1) {
        if (tid < off) sc[tid] = fmaxf(sc[tid], sc[tid + off]);
        __syncthreads();
    }
    m = sc[0];
    __syncthreads();
    float s = 0.f;
#pragma unroll
    for (int i = 0; i < 8; ++i) { d[i] = __expf(d[i] - m); s += d[i]; }
    sc[tid] = s;
    __syncthreads();
    for (int off = 128; off > 0; off >>= 1) {
        if (tid < off) sc[tid] += sc[tid + off];
        __syncthreads();
    }
    float inv = 1.f / sc[0];
    __syncthreads();
#pragma unroll
    for (int i = 0; i < 8; ++i) { d[i] *= inv; ds[base + i] = d[i]; }
    float g[8], p = 1.f;
#pragma unroll
    for (int i = 0; i < 8; ++i) {
        int t = base + i;
        float gv = (t == 0) ? 1.f : (1.f - d[i]);
        p *= gv;
        g[i] = p;
    }
    sc[tid] = p;
    __syncthreads();
    for (int off = 1; off < 256; off <<= 1) {
        float o = (tid >= off) ? sc[tid - off] : 1.f;
        float cur = sc[tid];
        __syncthreads();
        sc[tid] = cur * o;
        __syncthreads();
    }
    float pre = (tid > 0) ? sc[tid - 1] : 1.f;
    __syncthreads();
#pragma unroll
    for (int i = 0; i < 8; ++i) {
        int t = base + i;
        float budget = pre * g[i];
        float pt = (t < 2047) ? ds[t + 1] * budget : budget;
        pts[b * 2048 + t] = pt;
    }
}

extern "C" void kernel_launch(void* const* d_in, const int* in_sizes, int n_in,
                              void* d_out, int out_size, void* d_ws, size_t ws_size,
                              hipStream_t stream)
{
    const float* x     = (const float*)d_in[0];
    const float* w1    = (const float*)d_in[1];
    const float* b1    = (const float*)d_in[2];
    const float* w2    = (const float*)d_in[3];
    const float* b2    = (const float*)d_in[4];
    const float* w3    = (const float*)d_in[5];
    const float* b3    = (const float*)d_in[6];
    const float* w4    = (const float*)d_in[7];
    const float* b4    = (const float*)d_in[8];
    const float* gamma = (const float*)d_in[9];
    const float* beta  = (const float*)d_in[10];
    const float* mean  = (const float*)d_in[11];
    const float* var   = (const float*)d_in[12];
    const float* lw    = (const float*)d_in[13];
    const float* lb    = (const float*)d_in[14];
    const float* dw    = (const float*)d_in[15];
    const float* db    = (const float*)d_in[16];

    char* ws = (char*)d_ws;
    unsigned short* feat  = (unsigned short*)ws;                 // 67,108,864 B
    unsigned short* xT    = (unsigned short*)(ws + 67108864);    //  2,228,224 B
    unsigned short* Bfrag = (unsigned short*)(ws + 69337088);    //    409,600 B
    float* totals = (float*)(ws + 69746688);                     //    524,288 B
    float* prefix = (float*)(ws + 70270976);                     //    524,288 B
    float* draw   = (float*)(ws + 70795264);                     //    262,144 B
    float* wf     = (float*)(ws + 71057408);                     //     20,480 B
    float* dwf    = (float*)(ws + 71077888);                     //      2,048 B
    float* bf     = (float*)(ws + 71079936);                     //         64 B
    float* dbf    = (float*)(ws + 71080000);                     //         64 B

    float* probs = (float*)d_out;
    float* pts   = probs + (size_t)32 * 2048 * 10;

    hipLaunchKernelGGL(fold_kernel, dim3(1), dim3(512), 0, stream,
                       gamma, beta, mean, var, lw, lb, dw, db, wf, bf, dwf, dbf);
    hipLaunchKernelGGL(xt_prep, dim3(272), dim3(256), 0, stream, x, xT);
    hipLaunchKernelGGL(bfrag_prep, dim3(100), dim3(256), 0, stream, w1, w2, w3, w4, Bfrag);
    hipLaunchKernelGGL(conv_mfma, dim3(256), dim3(512), 0, stream,
                       xT, Bfrag, b1, b2, b3, b4, feat, totals);
    hipLaunchKernelGGL(prefix_kernel, dim3(64), dim3(256), 0, stream, totals, prefix);
    hipLaunchKernelGGL(head_kernel, dim3(256), dim3(256), 0, stream,
                       feat, prefix, wf, bf, dwf, dbf, probs, draw);
    hipLaunchKernelGGL(budget_kernel, dim3(32), dim3(256), 0, stream, draw, pts);
}

// Round 5
// 157.609 us; speedup vs baseline: 4.6092x; 1.3012x over previous
//
#include <hip/hip_runtime.h>
#include <math.h>

#define NEG_INF (-3.402823466e38f)

typedef float f32x4 __attribute__((ext_vector_type(4)));
typedef short bf16x8 __attribute__((ext_vector_type(8)));
typedef unsigned short u16x8 __attribute__((ext_vector_type(8)));

__device__ __forceinline__ unsigned short f2bf(float f) {
    unsigned int u = __float_as_uint(f);
    unsigned int r = (u + 0x7FFFu + ((u >> 16) & 1u)) >> 16;
    return (unsigned short)r;
}
__device__ __forceinline__ float bf2f(unsigned short s) {
    return __uint_as_float(((unsigned int)s) << 16);
}
// x-tile LDS swizzle (rows are 32B): XOR 16B-chunk bits with row&7. Applied on
// both staging writes and A-frag reads. Verified 0 conflicts in round 3.
__device__ __forceinline__ int swz(int a) { return a ^ (((a >> 5) & 7) << 4); }
// out-stage swizzle: 16t x 64h ushort tile, row=128B. XOR quad idx (8-ushort
// units) with ((row>>2)&3)<<1 -> per-instr rows hit disjoint quad pairs.
__device__ __forceinline__ int sws(int row, int col) {
    return row * 64 + (col ^ ((((row) >> 2) & 3) << 4));
}

// ---------------- fold BN into head weights ----------------
__global__ void fold_kernel(const float* __restrict__ bn_gamma,
                            const float* __restrict__ bn_beta,
                            const float* __restrict__ bn_mean,
                            const float* __restrict__ bn_var,
                            const float* __restrict__ lw, const float* __restrict__ lb,
                            const float* __restrict__ dw, const float* __restrict__ db,
                            float* __restrict__ wf, float* __restrict__ bf,
                            float* __restrict__ dwf, float* __restrict__ dbf)
{
    __shared__ float sh[512];
    int j = threadIdx.x;
    float s = rsqrtf(bn_var[j] + 1e-5f) * bn_gamma[j];
    float shift = bn_beta[j] - bn_mean[j] * s;
    sh[j] = shift;
#pragma unroll
    for (int c = 0; c < 10; ++c) wf[c * 512 + j] = lw[c * 512 + j] * s;
    dwf[j] = dw[j] * s;
    __syncthreads();
    if (j < 10) {
        float acc = lb[j];
        for (int q = 0; q < 512; ++q) acc += sh[q] * lw[j * 512 + q];
        bf[j] = acc;
    } else if (j == 10) {
        float acc = db[0];
        for (int q = 0; q < 512; ++q) acc += sh[q] * dw[q];
        dbf[0] = acc;
    }
}

// ---------------- prep: x -> xT bf16 [b][2176 rows][16c], row r = t + 20 ----
__global__ void xt_prep(const float* __restrict__ x, unsigned short* __restrict__ xT)
{
    int idx = blockIdx.x * 256 + threadIdx.x;   // b*2176 + r
    if (idx >= 32 * 2176) return;
    int b = idx / 2176, r = idx - b * 2176;
    int t = r - 20;
    unsigned short row[16];
#pragma unroll
    for (int c = 0; c < 16; ++c) {
        float v = (c < 13 && t >= 0 && t < 2048) ? x[((size_t)(b * 13 + c)) * 2048 + t] : 0.f;
        row[c] = f2bf(v);
    }
    uint4* dst = (uint4*)(xT + (size_t)idx * 16);
    uint4 v0, v1;
    v0.x = row[0] | ((unsigned)row[1] << 16);  v0.y = row[2] | ((unsigned)row[3] << 16);
    v0.z = row[4] | ((unsigned)row[5] << 16);  v0.w = row[6] | ((unsigned)row[7] << 16);
    v1.x = row[8] | ((unsigned)row[9] << 16);  v1.y = row[10] | ((unsigned)row[11] << 16);
    v1.z = row[12] | ((unsigned)row[13] << 16); v1.w = row[14] | ((unsigned)row[15] << 16);
    dst[0] = v0; dst[1] = v1;
}

// ---------------- prep: weights -> MFMA B-fragments (unchanged layout) ----
__global__ void bfrag_prep(const float* __restrict__ w1, const float* __restrict__ w2,
                           const float* __restrict__ w3, const float* __restrict__ w4,
                           unsigned short* __restrict__ Bfrag)
{
    int idx = blockIdx.x * 256 + threadIdx.x;   // frag*64 + lane
    if (idx >= 400 * 64) return;
    int lane = idx & 63, frag = idx >> 6;
    int rel, Kc; const float* w;
    if (frag < 40)       { rel = frag;       w = w1; Kc = 10; }
    else if (frag < 120) { rel = frag - 40;  w = w2; Kc = 20; }
    else if (frag < 240) { rel = frag - 120; w = w3; Kc = 30; }
    else                 { rel = frag - 240; w = w4; Kc = 40; }
    int kh = Kc / 2;
    int ht = rel / kh;
    int k0 = rel - ht * kh;
    int h = ht * 16 + (lane & 15);
    int dk = lane >> 5;
    int cbase = 8 * ((lane >> 4) & 1);
    int k = 2 * k0 + dk;
    unsigned short e[8];
#pragma unroll
    for (int j = 0; j < 8; ++j) {
        int c = cbase + j;
        float v = (c < 13) ? w[((size_t)h * 13 + c) * Kc + k] : 0.f;
        e[j] = f2bf(v);
    }
    uint4 pk;
    pk.x = e[0] | ((unsigned)e[1] << 16); pk.y = e[2] | ((unsigned)e[3] << 16);
    pk.z = e[4] | ((unsigned)e[5] << 16); pk.w = e[6] | ((unsigned)e[7] << 16);
    *(uint4*)(Bfrag + (size_t)frag * 512 + lane * 8) = pk;
}

// ---------------- conv via MFMA + local cummax + LDS-transpose store -------
// grid 2048 = b(32) x scale(4) x tq(16: 128t each). block 256 = 4 waves
// (2 hgrp x 2 twq). wave = 64h x 64t = 4 ht-tiles x 4 tt-tiles.
// per k0: 4 A ds_read_b128 + 4 B global(L2) + 16 MFMA. feat layout [b][t][512].
// NOTE: stg transpose readback is fenced with __syncthreads() on both sides —
// round-4 failure was an unfenced ushort-write -> uint4-read LDS round-trip
// (TBAA no-alias + unordered DS completion => replay-dependent divergence).
__global__ __launch_bounds__(256, 4) void conv_mfma(
    const unsigned short* __restrict__ xT, const unsigned short* __restrict__ Bfrag,
    const float* __restrict__ b1, const float* __restrict__ b2,
    const float* __restrict__ b3, const float* __restrict__ b4,
    unsigned short* __restrict__ feat, unsigned short* __restrict__ totals)
{
    __shared__ __align__(16) unsigned short lds[2688 + 4 * 1024];
    unsigned short* xs = lds;
    const int tid = threadIdx.x;
    const int tq = blockIdx.x & 15;
    const int scale = (blockIdx.x >> 4) & 3;
    const int b = blockIdx.x >> 6;
    const int kh_tab[4] = {5, 10, 15, 20};
    const int so_tab[4] = {0, 40, 120, 240};
    const int KH = kh_tab[scale];
    const int P = 5 * (scale + 1);
    const float* bias = (scale == 0) ? b1 : (scale == 1) ? b2 : (scale == 2) ? b3 : b4;

    // stage x rows [tq*128, tq*128+168) into LDS (swizzled), 336 x 16B chunks
    const unsigned short* src = xT + ((size_t)b * 2176 + tq * 128) * 16;
#pragma unroll
    for (int it = 0; it < 2; ++it) {
        int c = it * 256 + tid;
        if (c < 336) {
            uint4 v = *(const uint4*)(src + c * 8);
            *(uint4*)((char*)xs + swz(c * 16)) = v;
        }
    }
    __syncthreads();

    const int lane = tid & 63;
    const int wave = tid >> 6;
    const int hgrp = wave & 1;
    const int twq = wave >> 1;
    const int l15 = lane & 15;
    const int g4 = lane >> 4;

    const unsigned short* bfr = Bfrag + ((size_t)(so_tab[scale] + hgrp * 4 * KH)) * 512 + lane * 8;
    float bv[4];
#pragma unroll
    for (int ht = 0; ht < 4; ++ht) bv[ht] = bias[hgrp * 64 + ht * 16 + l15];

    // A byte addr (pre-swizzle): row = (20-P) + twq*64 + l15 + dk; half = g4&1
    int abase = ((20 - P) + twq * 64 + l15 + (lane >> 5)) * 32 + (g4 & 1) * 16;

    f32x4 acc[4][4];
#pragma unroll
    for (int ht = 0; ht < 4; ++ht)
#pragma unroll
        for (int tt = 0; tt < 4; ++tt)
            acc[ht][tt] = (f32x4){bv[ht], bv[ht], bv[ht], bv[ht]};

#pragma unroll 1
    for (int k0 = 0; k0 < KH; ++k0) {
        bf16x8 B[4], A[4];
#pragma unroll
        for (int ht = 0; ht < 4; ++ht)
            B[ht] = *(const bf16x8*)(bfr + (size_t)(ht * KH + k0) * 512);
#pragma unroll
        for (int tt = 0; tt < 4; ++tt)
            A[tt] = *(const bf16x8*)((const char*)xs + swz(abase + tt * 512 + k0 * 64));
#pragma unroll
        for (int ht = 0; ht < 4; ++ht)
#pragma unroll
            for (int tt = 0; tt < 4; ++tt)
                acc[ht][tt] = __builtin_amdgcn_mfma_f32_16x16x32_bf16(A[tt], B[ht], acc[ht][tt], 0, 0, 0);
    }

    // ---- cummax + per-wave LDS transpose + coalesced 128B-run stores ----
    unsigned short* stg = lds + 2688 + wave * 1024;   // 16t x 64h bf16 = 2KB
    float carry[4] = {NEG_INF, NEG_INF, NEG_INF, NEG_INF};
    const int rq = tq * 2 + twq;                      // 64t range index (0..31)

#pragma unroll 1
    for (int tt = 0; tt < 4; ++tt) {
#pragma unroll
        for (int ht = 0; ht < 4; ++ht) {
            f32x4 v = acc[ht][tt];
            float s0 = v.x;
            float s1 = fmaxf(v.y, s0);
            float s2 = fmaxf(v.z, s1);
            float s3 = fmaxf(v.w, s2);
            float inc = s3;
            float o = __shfl_up(inc, 16); if (lane >= 16) inc = fmaxf(inc, o);
            o = __shfl_up(inc, 32);       if (lane >= 32) inc = fmaxf(inc, o);
            float pre = __shfl_up(inc, 16);
            float base = (lane >= 16) ? fmaxf(carry[ht], pre) : carry[ht];
            s0 = fmaxf(s0, base); s1 = fmaxf(s1, base);
            s2 = fmaxf(s2, base); s3 = fmaxf(s3, base);
            float tot = __shfl(inc, l15 + 48);
            carry[ht] = fmaxf(carry[ht], tot);
            int col = ht * 16 + l15;
            stg[sws(4 * g4 + 0, col)] = f2bf(s0);
            stg[sws(4 * g4 + 1, col)] = f2bf(s1);
            stg[sws(4 * g4 + 2, col)] = f2bf(s2);
            stg[sws(4 * g4 + 3, col)] = f2bf(s3);
        }
        __syncthreads();   // RAW fence: all stg writes complete before readback
        // readback 16B chunks, store 8 rows x 128B contiguous per instr
        size_t grow = (size_t)b * 2048 + tq * 128 + twq * 64 + tt * 16;
#pragma unroll
        for (int i = 0; i < 2; ++i) {
            int e = i * 64 + lane;
            int row = e >> 3, q = e & 7;
            u16x8 val = *(const u16x8*)(stg + sws(row, q * 8));
            *(u16x8*)(feat + (grow + row) * 512 + scale * 128 + hgrp * 64 + q * 8) = val;
        }
        __syncthreads();   // WAR fence: readback done before next tt overwrites
    }
    if (lane < 16) {
#pragma unroll
        for (int ht = 0; ht < 4; ++ht) {
            int j = scale * 128 + hgrp * 64 + ht * 16 + lane;
            totals[((size_t)b * 512 + j) * 32 + rq] = f2bf(carry[ht]);
        }
    }
}

// ------ in-place exclusive prefix-max over the 32 t-ranges per (b,j) -------
// bf16 exact: f2bf(max(a,b)) == max(f2bf(a), f2bf(b)) (monotone rounding).
__global__ void prefix_kernel(unsigned short* __restrict__ totals)
{
    int idx = blockIdx.x * 256 + threadIdx.x;
    if (idx >= 32 * 512) return;
    float run = NEG_INF;
#pragma unroll
    for (int q = 0; q < 32; ++q) {
        float v = bf2f(totals[(size_t)idx * 32 + q]);
        totals[(size_t)idx * 32 + q] = f2bf(run);
        run = fmaxf(run, v);
    }
}

// ---------------- head: prefix fixup + logits softmax + delta raw ----------
// grid 1024 = b(32) x tc(32: 64t). block 256 = 4 j-quarters x 64 t.
__global__ __launch_bounds__(256) void head_kernel(
    const unsigned short* __restrict__ feat, const unsigned short* __restrict__ prefix,
    const float* __restrict__ wf, const float* __restrict__ bf,
    const float* __restrict__ dwf, const float* __restrict__ dbf,
    float* __restrict__ probs, float* __restrict__ delta_raw)
{
    __shared__ float pfs[512];
    __shared__ float part[4][64][13];
    int b = blockIdx.x >> 5;
    int tc = blockIdx.x & 31;
    int tid = threadIdx.x;
    int q = tid >> 6, tl = tid & 63;
    int t = tc * 64 + tl;
    for (int j = tid; j < 512; j += 256)
        pfs[j] = bf2f(prefix[((size_t)b * 512 + j) * 32 + tc]);
    __syncthreads();

    float acc[11];
#pragma unroll
    for (int c = 0; c < 11; ++c) acc[c] = 0.f;
    const unsigned short* fb = feat + ((size_t)b * 2048 + t) * 512 + q * 128;
#pragma unroll 2
    for (int i = 0; i < 16; ++i) {
        bf16x8 v8 = *(const bf16x8*)(fb + i * 8);
        int jb = q * 128 + i * 8;
#pragma unroll
        for (int e = 0; e < 8; ++e) {
            float v = fmaxf(bf2f((unsigned short)v8[e]), pfs[jb + e]);
#pragma unroll
            for (int c = 0; c < 10; ++c) acc[c] = fmaf(v, wf[c * 512 + jb + e], acc[c]);
            acc[10] = fmaf(v, dwf[jb + e], acc[10]);
        }
    }
#pragma unroll
    for (int c = 0; c < 11; ++c) part[q][tl][c] = acc[c];
    __syncthreads();

    if (tid < 64) {
        float s[11];
#pragma unroll
        for (int c = 0; c < 11; ++c)
            s[c] = part[0][tid][c] + part[1][tid][c] + part[2][tid][c] + part[3][tid][c];
#pragma unroll
        for (int c = 0; c < 10; ++c) s[c] += bf[c];
        s[10] += dbf[0];
        float m = s[0];
#pragma unroll
        for (int c = 1; c < 10; ++c) m = fmaxf(m, s[c]);
        float sum = 0.f;
        float e[10];
#pragma unroll
        for (int c = 0; c < 10; ++c) { e[c] = __expf(s[c] - m); sum += e[c]; }
        float inv = 1.f / sum;
        int tt = tc * 64 + tid;
        float* po = probs + ((size_t)b * 2048 + tt) * 10;
#pragma unroll
        for (int c = 0; c < 10; ++c) po[c] = e[c] * inv;
        delta_raw[b * 2048 + tt] = s[10];
    }
}

// ---------------- softmax over T + budget chain ----------------
__global__ __launch_bounds__(256) void budget_kernel(
    const float* __restrict__ delta_raw, float* __restrict__ pts)
{
    __shared__ float ds[2048];
    __shared__ float sc[256];
    int b = blockIdx.x;
    int tid = threadIdx.x;
    const float* row = delta_raw + b * 2048;
    int base = tid * 8;
    float d[8];
#pragma unroll
    for (int i = 0; i < 8; ++i) d[i] = row[base + i];
    float m = d[0];
#pragma unroll
    for (int i = 1; i < 8; ++i) m = fmaxf(m, d[i]);
    sc[tid] = m;
    __syncthreads();
    for (int off = 128; off > 0; off >>= 1) {
        if (tid < off) sc[tid] = fmaxf(sc[tid], sc[tid + off]);
        __syncthreads();
    }
    m = sc[0];
    __syncthreads();
    float s = 0.f;
#pragma unroll
    for (int i = 0; i < 8; ++i) { d[i] = __expf(d[i] - m); s += d[i]; }
    sc[tid] = s;
    __syncthreads();
    for (int off = 128; off > 0; off >>= 1) {
        if (tid < off) sc[tid] += sc[tid + off];
        __syncthreads();
    }
    float inv = 1.f / sc[0];
    __syncthreads();
#pragma unroll
    for (int i = 0; i < 8; ++i) { d[i] *= inv; ds[base + i] = d[i]; }
    float g[8], p = 1.f;
#pragma unroll
    for (int i = 0; i < 8; ++i) {
        int t = base + i;
        float gv = (t == 0) ? 1.f : (1.f - d[i]);
        p *= gv;
        g[i] = p;
    }
    sc[tid] = p;
    __syncthreads();
    for (int off = 1; off < 256; off <<= 1) {
        float o = (tid >= off) ? sc[tid - off] : 1.f;
        float cur = sc[tid];
        __syncthreads();
        sc[tid] = cur * o;
        __syncthreads();
    }
    float pre = (tid > 0) ? sc[tid - 1] : 1.f;
    __syncthreads();
#pragma unroll
    for (int i = 0; i < 8; ++i) {
        int t = base + i;
        float budget = pre * g[i];
        float pt = (t < 2047) ? ds[t + 1] * budget : budget;
        pts[b * 2048 + t] = pt;
    }
}

extern "C" void kernel_launch(void* const* d_in, const int* in_sizes, int n_in,
                              void* d_out, int out_size, void* d_ws, size_t ws_size,
                              hipStream_t stream)
{
    const float* x     = (const float*)d_in[0];
    const float* w1    = (const float*)d_in[1];
    const float* b1    = (const float*)d_in[2];
    const float* w2    = (const float*)d_in[3];
    const float* b2    = (const float*)d_in[4];
    const float* w3    = (const float*)d_in[5];
    const float* b3    = (const float*)d_in[6];
    const float* w4    = (const float*)d_in[7];
    const float* b4    = (const float*)d_in[8];
    const float* gamma = (const float*)d_in[9];
    const float* beta  = (const float*)d_in[10];
    const float* mean  = (const float*)d_in[11];
    const float* var   = (const float*)d_in[12];
    const float* lw    = (const float*)d_in[13];
    const float* lb    = (const float*)d_in[14];
    const float* dw    = (const float*)d_in[15];
    const float* db    = (const float*)d_in[16];

    char* ws = (char*)d_ws;
    unsigned short* feat   = (unsigned short*)ws;                 // 67,108,864 B
    unsigned short* xT     = (unsigned short*)(ws + 67108864);    //  2,228,224 B
    unsigned short* Bfrag  = (unsigned short*)(ws + 69337088);    //    409,600 B
    unsigned short* totals = (unsigned short*)(ws + 69746688);    //  1,048,576 B
    float* draw   = (float*)(ws + 70795264);                      //    262,144 B
    float* wf     = (float*)(ws + 71057408);                      //     20,480 B
    float* dwf    = (float*)(ws + 71077888);                      //      2,048 B
    float* bf     = (float*)(ws + 71079936);                      //         64 B
    float* dbf    = (float*)(ws + 71080000);                      //         64 B
    // total ws use: 71,080,064 B (== round-3 proven footprint)

    float* probs = (float*)d_out;
    float* pts   = probs + (size_t)32 * 2048 * 10;

    hipLaunchKernelGGL(fold_kernel, dim3(1), dim3(512), 0, stream,
                       gamma, beta, mean, var, lw, lb, dw, db, wf, bf, dwf, dbf);
    hipLaunchKernelGGL(xt_prep, dim3(272), dim3(256), 0, stream, x, xT);
    hipLaunchKernelGGL(bfrag_prep, dim3(100), dim3(256), 0, stream, w1, w2, w3, w4, Bfrag);
    hipLaunchKernelGGL(conv_mfma, dim3(2048), dim3(256), 0, stream,
                       xT, Bfrag, b1, b2, b3, b4, feat, totals);
    hipLaunchKernelGGL(prefix_kernel, dim3(64), dim3(256), 0, stream, totals);
    hipLaunchKernelGGL(head_kernel, dim3(1024), dim3(256), 0, stream,
                       feat, totals, wf, bf, dwf, dbf, probs, draw);
    hipLaunchKernelGGL(budget_kernel, dim3(32), dim3(256), 0, stream, draw, pts);
}

// Round 6
// 120.072 us; speedup vs baseline: 6.0501x; 1.3126x over previous
//
#include <hip/hip_runtime.h>
#include <math.h>

#define NEG_INF (-3.402823466e38f)

typedef float f32x4 __attribute__((ext_vector_type(4)));
typedef short bf16x8 __attribute__((ext_vector_type(8)));

__device__ __forceinline__ unsigned short f2bf(float f) {
    unsigned int u = __float_as_uint(f);
    unsigned int r = (u + 0x7FFFu + ((u >> 16) & 1u)) >> 16;
    return (unsigned short)r;
}
__device__ __forceinline__ float bf2f(unsigned short s) {
    return __uint_as_float(((unsigned int)s) << 16);
}
__device__ __forceinline__ unsigned int pack2(float a, float b) {
    return (unsigned int)f2bf(a) | ((unsigned int)f2bf(b) << 16);
}
// x-tile LDS swizzle (rows are 32B): XOR 16B-chunk bits with row&7. Applied on
// both staging writes and A-frag reads. Verified 0 conflicts in rounds 3/5.
__device__ __forceinline__ int swz(int a) { return a ^ (((a >> 5) & 7) << 4); }

// ---------------- prep: fold BN + xT + B-frags in one launch ----------------
__global__ __launch_bounds__(512) void prep_kernel(
    const float* __restrict__ x,
    const float* __restrict__ w1, const float* __restrict__ w2,
    const float* __restrict__ w3, const float* __restrict__ w4,
    const float* __restrict__ bn_gamma, const float* __restrict__ bn_beta,
    const float* __restrict__ bn_mean, const float* __restrict__ bn_var,
    const float* __restrict__ lw, const float* __restrict__ lb,
    const float* __restrict__ dw, const float* __restrict__ db,
    unsigned short* __restrict__ xT, unsigned short* __restrict__ Bfrag,
    float* __restrict__ wf, float* __restrict__ bf,
    float* __restrict__ dwf, float* __restrict__ dbf)
{
    int bid = blockIdx.x;
    int tid = threadIdx.x;
    if (bid < 136) {
        // ---- xT: x -> bf16 [b][2176 rows][16c], row r = t + 20 ----
        int idx = bid * 512 + tid;           // b*2176 + r, < 69632 exact
        int b = idx / 2176, r = idx - b * 2176;
        int t = r - 20;
        unsigned short row[16];
#pragma unroll
        for (int c = 0; c < 16; ++c) {
            float v = (c < 13 && t >= 0 && t < 2048) ? x[((size_t)(b * 13 + c)) * 2048 + t] : 0.f;
            row[c] = f2bf(v);
        }
        uint4* dst = (uint4*)(xT + (size_t)idx * 16);
        uint4 v0, v1;
        v0.x = row[0] | ((unsigned)row[1] << 16);  v0.y = row[2] | ((unsigned)row[3] << 16);
        v0.z = row[4] | ((unsigned)row[5] << 16);  v0.w = row[6] | ((unsigned)row[7] << 16);
        v1.x = row[8] | ((unsigned)row[9] << 16);  v1.y = row[10] | ((unsigned)row[11] << 16);
        v1.z = row[12] | ((unsigned)row[13] << 16); v1.w = row[14] | ((unsigned)row[15] << 16);
        dst[0] = v0; dst[1] = v1;
    } else if (bid < 186) {
        // ---- Bfrag: weights -> MFMA B-fragment lane layout ----
        int idx = (bid - 136) * 512 + tid;   // frag*64 + lane, < 25600 exact
        int lane = idx & 63, frag = idx >> 6;
        int rel, Kc; const float* w;
        if (frag < 40)       { rel = frag;       w = w1; Kc = 10; }
        else if (frag < 120) { rel = frag - 40;  w = w2; Kc = 20; }
        else if (frag < 240) { rel = frag - 120; w = w3; Kc = 30; }
        else                 { rel = frag - 240; w = w4; Kc = 40; }
        int kh = Kc / 2;
        int ht = rel / kh;
        int k0 = rel - ht * kh;
        int h = ht * 16 + (lane & 15);
        int dk = lane >> 5;
        int cbase = 8 * ((lane >> 4) & 1);
        int k = 2 * k0 + dk;
        unsigned short e[8];
#pragma unroll
        for (int j = 0; j < 8; ++j) {
            int c = cbase + j;
            float v = (c < 13) ? w[((size_t)h * 13 + c) * Kc + k] : 0.f;
            e[j] = f2bf(v);
        }
        uint4 pk;
        pk.x = e[0] | ((unsigned)e[1] << 16); pk.y = e[2] | ((unsigned)e[3] << 16);
        pk.z = e[4] | ((unsigned)e[5] << 16); pk.w = e[6] | ((unsigned)e[7] << 16);
        *(uint4*)(Bfrag + (size_t)frag * 512 + lane * 8) = pk;
    } else {
        // ---- fold BN into head weights ----
        __shared__ float sh[512];
        int j = tid;
        float s = rsqrtf(bn_var[j] + 1e-5f) * bn_gamma[j];
        float shift = bn_beta[j] - bn_mean[j] * s;
        sh[j] = shift;
#pragma unroll
        for (int c = 0; c < 10; ++c) wf[c * 512 + j] = lw[c * 512 + j] * s;
        dwf[j] = dw[j] * s;
        __syncthreads();
        if (j < 10) {
            float acc = lb[j];
            for (int q = 0; q < 512; ++q) acc += sh[q] * lw[j * 512 + q];
            bf[j] = acc;
        } else if (j == 10) {
            float acc = db[0];
            for (int q = 0; q < 512; ++q) acc += sh[q] * dw[q];
            dbf[0] = acc;
        }
    }
}

// ---------------- conv via MFMA + local cummax + LDS-transpose store -------
// grid 2048 = b(32) x scale(4) x tq(16: 128t each). block 256 = 4 waves
// (2 hgrp x 2 twq). wave = 64h x 64t.
// Epilogue: t-pair-interleaved dword stage [64 t-pairs][128 h] (+132-dword
// padded rows -> <=2-way banks), ONE barrier, uint4 readback + even/odd
// unpack -> 256B-contiguous feat rows. totals layout [b][rq 32][j 512]:
// 16-lane contiguous 2B runs (fixes round-5's 64MB RMW-fetch thrash).
__global__ __launch_bounds__(256, 4) void conv_mfma(
    const unsigned short* __restrict__ xT, const unsigned short* __restrict__ Bfrag,
    const float* __restrict__ b1, const float* __restrict__ b2,
    const float* __restrict__ b3, const float* __restrict__ b4,
    unsigned short* __restrict__ feat, unsigned short* __restrict__ totals)
{
    __shared__ __align__(16) unsigned short lds[2688 + 2 * 64 * 132];
    unsigned short* xs = lds;
    unsigned int* stg32 = (unsigned int*)(lds + 2688);   // [64 r2][132 pad] dwords
    const int tid = threadIdx.x;
    const int tq = blockIdx.x & 15;
    const int scale = (blockIdx.x >> 4) & 3;
    const int b = blockIdx.x >> 6;
    const int kh_tab[4] = {5, 10, 15, 20};
    const int so_tab[4] = {0, 40, 120, 240};
    const int KH = kh_tab[scale];
    const int P = 5 * (scale + 1);
    const float* bias = (scale == 0) ? b1 : (scale == 1) ? b2 : (scale == 2) ? b3 : b4;

    // stage x rows [tq*128, tq*128+168) into LDS (swizzled), 336 x 16B chunks
    const unsigned short* src = xT + ((size_t)b * 2176 + tq * 128) * 16;
#pragma unroll
    for (int it = 0; it < 2; ++it) {
        int c = it * 256 + tid;
        if (c < 336) {
            uint4 v = *(const uint4*)(src + c * 8);
            *(uint4*)((char*)xs + swz(c * 16)) = v;
        }
    }
    __syncthreads();

    const int lane = tid & 63;
    const int wave = tid >> 6;
    const int hgrp = wave & 1;
    const int twq = wave >> 1;
    const int l15 = lane & 15;
    const int g4 = lane >> 4;

    const unsigned short* bfr = Bfrag + ((size_t)(so_tab[scale] + hgrp * 4 * KH)) * 512 + lane * 8;
    float bv[4];
#pragma unroll
    for (int ht = 0; ht < 4; ++ht) bv[ht] = bias[hgrp * 64 + ht * 16 + l15];

    // A byte addr (pre-swizzle): row = (20-P) + twq*64 + l15 + dk; half = g4&1
    int abase = ((20 - P) + twq * 64 + l15 + (lane >> 5)) * 32 + (g4 & 1) * 16;

    f32x4 acc[4][4];
#pragma unroll
    for (int ht = 0; ht < 4; ++ht)
#pragma unroll
        for (int tt = 0; tt < 4; ++tt)
            acc[ht][tt] = (f32x4){bv[ht], bv[ht], bv[ht], bv[ht]};

#pragma unroll 1
    for (int k0 = 0; k0 < KH; ++k0) {
        bf16x8 B[4], A[4];
#pragma unroll
        for (int ht = 0; ht < 4; ++ht)
            B[ht] = *(const bf16x8*)(bfr + (size_t)(ht * KH + k0) * 512);
#pragma unroll
        for (int tt = 0; tt < 4; ++tt)
            A[tt] = *(const bf16x8*)((const char*)xs + swz(abase + tt * 512 + k0 * 64));
#pragma unroll
        for (int ht = 0; ht < 4; ++ht)
#pragma unroll
            for (int tt = 0; tt < 4; ++tt)
                acc[ht][tt] = __builtin_amdgcn_mfma_f32_16x16x32_bf16(A[tt], B[ht], acc[ht][tt], 0, 0, 0);
    }

    // ---- cummax scan; write t-pair-packed dwords into block stage ----
    float carry[4] = {NEG_INF, NEG_INF, NEG_INF, NEG_INF};
    const int rq = tq * 2 + twq;                      // 64t range index (0..31)
    const int col = hgrp * 64 + l15;                  // + ht*16 below

#pragma unroll
    for (int tt = 0; tt < 4; ++tt) {
#pragma unroll
        for (int ht = 0; ht < 4; ++ht) {
            f32x4 v = acc[ht][tt];
            float s0 = v.x;
            float s1 = fmaxf(v.y, s0);
            float s2 = fmaxf(v.z, s1);
            float s3 = fmaxf(v.w, s2);
            float inc = s3;
            float o = __shfl_up(inc, 16); if (lane >= 16) inc = fmaxf(inc, o);
            o = __shfl_up(inc, 32);       if (lane >= 32) inc = fmaxf(inc, o);
            float pre = __shfl_up(inc, 16);
            float base = (lane >= 16) ? fmaxf(carry[ht], pre) : carry[ht];
            s0 = fmaxf(s0, base); s1 = fmaxf(s1, base);
            s2 = fmaxf(s2, base); s3 = fmaxf(s3, base);
            float tot = __shfl(inc, l15 + 48);
            carry[ht] = fmaxf(carry[ht], tot);
            // t0 = twq*64 + tt*16 + 4*g4 (even); r2 = t0/2
            int r2 = twq * 32 + tt * 8 + 2 * g4;
            int cc = col + ht * 16;
            stg32[r2 * 132 + cc]       = pack2(s0, s1);
            stg32[(r2 + 1) * 132 + cc] = pack2(s2, s3);
        }
    }
    // totals[b][rq][j]: 16-lane contiguous 2B runs (one 128B line per wave)
    if (lane < 16) {
#pragma unroll
        for (int ht = 0; ht < 4; ++ht) {
            int j = scale * 128 + hgrp * 64 + ht * 16 + l15;
            totals[((size_t)b * 32 + rq) * 512 + j] = f2bf(carry[ht]);
        }
    }
    __syncthreads();   // RAW fence: stage complete before readback

    // readback: per thread-iter 2 uint4 LDS reads -> even/odd t unpack ->
    // two 16B stores; per instr: 4 rows x 256B contiguous feat runs
    size_t grow = (size_t)b * 2048 + tq * 128;
#pragma unroll
    for (int i = 0; i < 4; ++i) {
        int e = i * 256 + tid;               // 0..1023 = 64 r2 x 16 q
        int r2 = e >> 4, q = e & 15;
        const unsigned int* p = stg32 + r2 * 132 + q * 8;
        uint4 da = *(const uint4*)(p);
        uint4 db = *(const uint4*)(p + 4);
        uint4 ev, od;
        ev.x = (da.x & 0xffffu) | (da.y << 16);
        ev.y = (da.z & 0xffffu) | (da.w << 16);
        ev.z = (db.x & 0xffffu) | (db.y << 16);
        ev.w = (db.z & 0xffffu) | (db.w << 16);
        od.x = (da.x >> 16) | (da.y & 0xffff0000u);
        od.y = (da.z >> 16) | (da.w & 0xffff0000u);
        od.z = (db.x >> 16) | (db.y & 0xffff0000u);
        od.w = (db.z >> 16) | (db.w & 0xffff0000u);
        size_t base = (grow + 2 * r2) * 512 + scale * 128 + q * 8;
        *(uint4*)(feat + base)       = ev;   // t = 2*r2
        *(uint4*)(feat + base + 512) = od;   // t = 2*r2+1
    }
}

// ---------------- head: prefix + fixup + logits softmax + delta raw --------
// grid 1024 = b(32) x tc(32: 64t). block 256 = 4 j-quarters x 64 t.
// Exclusive prefix-max over totals[b][q<tc][j] computed in-block (coalesced).
__global__ __launch_bounds__(256) void head_kernel(
    const unsigned short* __restrict__ feat, const unsigned short* __restrict__ totals,
    const float* __restrict__ wf, const float* __restrict__ bf,
    const float* __restrict__ dwf, const float* __restrict__ dbf,
    float* __restrict__ probs, float* __restrict__ delta_raw)
{
    __shared__ float pfs[512];
    __shared__ float part[4][64][13];
    int b = blockIdx.x >> 5;
    int tc = blockIdx.x & 31;
    int tid = threadIdx.x;
    int q = tid >> 6, tl = tid & 63;
    int t = tc * 64 + tl;
    for (int j = tid; j < 512; j += 256) {
        float run = NEG_INF;
        for (int qq = 0; qq < tc; ++qq)
            run = fmaxf(run, bf2f(totals[((size_t)b * 32 + qq) * 512 + j]));
        pfs[j] = run;
    }
    __syncthreads();

    float acc[11];
#pragma unroll
    for (int c = 0; c < 11; ++c) acc[c] = 0.f;
    const unsigned short* fb = feat + ((size_t)b * 2048 + t) * 512 + q * 128;
#pragma unroll 2
    for (int i = 0; i < 16; ++i) {
        bf16x8 v8 = *(const bf16x8*)(fb + i * 8);
        int jb = q * 128 + i * 8;
#pragma unroll
        for (int e = 0; e < 8; ++e) {
            float v = fmaxf(bf2f((unsigned short)v8[e]), pfs[jb + e]);
#pragma unroll
            for (int c = 0; c < 10; ++c) acc[c] = fmaf(v, wf[c * 512 + jb + e], acc[c]);
            acc[10] = fmaf(v, dwf[jb + e], acc[10]);
        }
    }
#pragma unroll
    for (int c = 0; c < 11; ++c) part[q][tl][c] = acc[c];
    __syncthreads();

    if (tid < 64) {
        float s[11];
#pragma unroll
        for (int c = 0; c < 11; ++c)
            s[c] = part[0][tid][c] + part[1][tid][c] + part[2][tid][c] + part[3][tid][c];
#pragma unroll
        for (int c = 0; c < 10; ++c) s[c] += bf[c];
        s[10] += dbf[0];
        float m = s[0];
#pragma unroll
        for (int c = 1; c < 10; ++c) m = fmaxf(m, s[c]);
        float sum = 0.f;
        float e[10];
#pragma unroll
        for (int c = 0; c < 10; ++c) { e[c] = __expf(s[c] - m); sum += e[c]; }
        float inv = 1.f / sum;
        int tt = tc * 64 + tid;
        float* po = probs + ((size_t)b * 2048 + tt) * 10;
#pragma unroll
        for (int c = 0; c < 10; ++c) po[c] = e[c] * inv;
        delta_raw[b * 2048 + tt] = s[10];
    }
}

// ---------------- softmax over T + budget chain ----------------
__global__ __launch_bounds__(256) void budget_kernel(
    const float* __restrict__ delta_raw, float* __restrict__ pts)
{
    __shared__ float ds[2048];
    __shared__ float sc[256];
    int b = blockIdx.x;
    int tid = threadIdx.x;
    const float* row = delta_raw + b * 2048;
    int base = tid * 8;
    float d[8];
#pragma unroll
    for (int i = 0; i < 8; ++i) d[i] = row[base + i];
    float m = d[0];
#pragma unroll
    for (int i = 1; i < 8; ++i) m = fmaxf(m, d[i]);
    sc[tid] = m;
    __syncthreads();
    for (int off = 128; off > 0; off >>= 1) {
        if (tid < off) sc[tid] = fmaxf(sc[tid], sc[tid + off]);
        __syncthreads();
    }
    m = sc[0];
    __syncthreads();
    float s = 0.f;
#pragma unroll
    for (int i = 0; i < 8; ++i) { d[i] = __expf(d[i] - m); s += d[i]; }
    sc[tid] = s;
    __syncthreads();
    for (int off = 128; off > 0; off >>= 1) {
        if (tid < off) sc[tid] += sc[tid + off];
        __syncthreads();
    }
    float inv = 1.f / sc[0];
    __syncthreads();
#pragma unroll
    for (int i = 0; i < 8; ++i) { d[i] *= inv; ds[base + i] = d[i]; }
    float g[8], p = 1.f;
#pragma unroll
    for (int i = 0; i < 8; ++i) {
        int t = base + i;
        float gv = (t == 0) ? 1.f : (1.f - d[i]);
        p *= gv;
        g[i] = p;
    }
    sc[tid] = p;
    __syncthreads();
    for (int off = 1; off < 256; off <<= 1) {
        float o = (tid >= off) ? sc[tid - off] : 1.f;
        float cur = sc[tid];
        __syncthreads();
        sc[tid] = cur * o;
        __syncthreads();
    }
    float pre = (tid > 0) ? sc[tid - 1] : 1.f;
    __syncthreads();
#pragma unroll
    for (int i = 0; i < 8; ++i) {
        int t = base + i;
        float budget = pre * g[i];
        float pt = (t < 2047) ? ds[t + 1] * budget : budget;
        pts[b * 2048 + t] = pt;
    }
}

extern "C" void kernel_launch(void* const* d_in, const int* in_sizes, int n_in,
                              void* d_out, int out_size, void* d_ws, size_t ws_size,
                              hipStream_t stream)
{
    const float* x     = (const float*)d_in[0];
    const float* w1    = (const float*)d_in[1];
    const float* b1    = (const float*)d_in[2];
    const float* w2    = (const float*)d_in[3];
    const float* b2    = (const float*)d_in[4];
    const float* w3    = (const float*)d_in[5];
    const float* b3    = (const float*)d_in[6];
    const float* w4    = (const float*)d_in[7];
    const float* b4    = (const float*)d_in[8];
    const float* gamma = (const float*)d_in[9];
    const float* beta  = (const float*)d_in[10];
    const float* mean  = (const float*)d_in[11];
    const float* var   = (const float*)d_in[12];
    const float* lw    = (const float*)d_in[13];
    const float* lb    = (const float*)d_in[14];
    const float* dw    = (const float*)d_in[15];
    const float* db    = (const float*)d_in[16];

    char* ws = (char*)d_ws;
    unsigned short* feat   = (unsigned short*)ws;                 // 67,108,864 B
    unsigned short* xT     = (unsigned short*)(ws + 67108864);    //  2,228,224 B
    unsigned short* Bfrag  = (unsigned short*)(ws + 69337088);    //    409,600 B
    unsigned short* totals = (unsigned short*)(ws + 69746688);    //  1,048,576 B
    float* draw   = (float*)(ws + 70795264);                      //    262,144 B
    float* wf     = (float*)(ws + 71057408);                      //     20,480 B
    float* dwf    = (float*)(ws + 71077888);                      //      2,048 B
    float* bf     = (float*)(ws + 71079936);                      //         64 B
    float* dbf    = (float*)(ws + 71080000);                      //         64 B
    // total ws use: 71,080,064 B (proven footprint)

    float* probs = (float*)d_out;
    float* pts   = probs + (size_t)32 * 2048 * 10;

    hipLaunchKernelGGL(prep_kernel, dim3(187), dim3(512), 0, stream,
                       x, w1, w2, w3, w4, gamma, beta, mean, var,
                       lw, lb, dw, db, xT, Bfrag, wf, bf, dwf, dbf);
    hipLaunchKernelGGL(conv_mfma, dim3(2048), dim3(256), 0, stream,
                       xT, Bfrag, b1, b2, b3, b4, feat, totals);
    hipLaunchKernelGGL(head_kernel, dim3(1024), dim3(256), 0, stream,
                       feat, totals, wf, bf, dwf, dbf, probs, draw);
    hipLaunchKernelGGL(budget_kernel, dim3(32), dim3(256), 0, stream, draw, pts);
}

// Round 7
// 87.415 us; speedup vs baseline: 8.3104x; 1.3736x over previous
//
#include <hip/hip_runtime.h>
#include <math.h>

#define NEG_INF (-3.402823466e38f)

typedef float f32x4 __attribute__((ext_vector_type(4)));
typedef short bf16x8 __attribute__((ext_vector_type(8)));

__device__ __forceinline__ unsigned short f2bf(float f) {
    unsigned int u = __float_as_uint(f);
    unsigned int r = (u + 0x7FFFu + ((u >> 16) & 1u)) >> 16;
    return (unsigned short)r;
}
__device__ __forceinline__ float bf2f(unsigned short s) {
    return __uint_as_float(((unsigned int)s) << 16);
}
__device__ __forceinline__ unsigned int pack2(float a, float b) {
    return (unsigned int)f2bf(a) | ((unsigned int)f2bf(b) << 16);
}
// x-tile LDS swizzle (rows are 32B): XOR 16B-chunk bits with row&7.
__device__ __forceinline__ int swz(int a) { return a ^ (((a >> 5) & 7) << 4); }

// ---------------- prep: xT + conv B-frags + head B-frags + bias fold --------
__global__ __launch_bounds__(512) void prep_kernel(
    const float* __restrict__ x,
    const float* __restrict__ w1, const float* __restrict__ w2,
    const float* __restrict__ w3, const float* __restrict__ w4,
    const float* __restrict__ bn_gamma, const float* __restrict__ bn_beta,
    const float* __restrict__ bn_mean, const float* __restrict__ bn_var,
    const float* __restrict__ lw, const float* __restrict__ lb,
    const float* __restrict__ dw, const float* __restrict__ db,
    unsigned short* __restrict__ xT, unsigned short* __restrict__ Bfrag,
    unsigned short* __restrict__ hfrag, float* __restrict__ bfo,
    float* __restrict__ dbfo)
{
    int bid = blockIdx.x;
    int tid = threadIdx.x;
    if (bid < 136) {
        // ---- xT: x -> bf16 [b][2176 rows][16c], row r = t + 20 ----
        int idx = bid * 512 + tid;           // b*2176 + r, < 69632 exact
        int b = idx / 2176, r = idx - b * 2176;
        int t = r - 20;
        unsigned short row[16];
#pragma unroll
        for (int c = 0; c < 16; ++c) {
            float v = (c < 13 && t >= 0 && t < 2048) ? x[((size_t)(b * 13 + c)) * 2048 + t] : 0.f;
            row[c] = f2bf(v);
        }
        uint4* dst = (uint4*)(xT + (size_t)idx * 16);
        uint4 v0, v1;
        v0.x = row[0] | ((unsigned)row[1] << 16);  v0.y = row[2] | ((unsigned)row[3] << 16);
        v0.z = row[4] | ((unsigned)row[5] << 16);  v0.w = row[6] | ((unsigned)row[7] << 16);
        v1.x = row[8] | ((unsigned)row[9] << 16);  v1.y = row[10] | ((unsigned)row[11] << 16);
        v1.z = row[12] | ((unsigned)row[13] << 16); v1.w = row[14] | ((unsigned)row[15] << 16);
        dst[0] = v0; dst[1] = v1;
    } else if (bid < 186) {
        // ---- Bfrag: conv weights -> MFMA B-fragment lane layout ----
        int idx = (bid - 136) * 512 + tid;   // frag*64 + lane, < 25600 exact
        int lane = idx & 63, frag = idx >> 6;
        int rel, Kc; const float* w;
        if (frag < 40)       { rel = frag;       w = w1; Kc = 10; }
        else if (frag < 120) { rel = frag - 40;  w = w2; Kc = 20; }
        else if (frag < 240) { rel = frag - 120; w = w3; Kc = 30; }
        else                 { rel = frag - 240; w = w4; Kc = 40; }
        int kh = Kc / 2;
        int ht = rel / kh;
        int k0 = rel - ht * kh;
        int h = ht * 16 + (lane & 15);
        int dk = lane >> 5;
        int cbase = 8 * ((lane >> 4) & 1);
        int k = 2 * k0 + dk;
        unsigned short e[8];
#pragma unroll
        for (int j = 0; j < 8; ++j) {
            int c = cbase + j;
            float v = (c < 13) ? w[((size_t)h * 13 + c) * Kc + k] : 0.f;
            e[j] = f2bf(v);
        }
        uint4 pk;
        pk.x = e[0] | ((unsigned)e[1] << 16); pk.y = e[2] | ((unsigned)e[3] << 16);
        pk.z = e[4] | ((unsigned)e[5] << 16); pk.w = e[6] | ((unsigned)e[7] << 16);
        *(uint4*)(Bfrag + (size_t)frag * 512 + lane * 8) = pk;
    } else if (bid == 186) {
        // ---- fold BN shift into head biases (fp32, used post-MFMA) ----
        __shared__ float sh[512];
        int j = tid;
        float s = rsqrtf(bn_var[j] + 1e-5f) * bn_gamma[j];
        float shift = bn_beta[j] - bn_mean[j] * s;
        sh[j] = shift;
        __syncthreads();
        if (j < 10) {
            float acc = lb[j];
            for (int q = 0; q < 512; ++q) acc += sh[q] * lw[j * 512 + q];
            bfo[j] = acc;
        } else if (j == 10) {
            float acc = db[0];
            for (int q = 0; q < 512; ++q) acc += sh[q] * dw[q];
            dbfo[0] = acc;
        }
    } else {
        // ---- hfrag: head weights (BN-scale folded) -> B-frag layout ----
        // B[kdim][n]: n = lane&15 (0..9 logits, 10 delta, 11..15 zero),
        // kdim = 8*(lane>>4)+jj, k = frag*32 + kdim.
        int idx = (bid - 187) * 512 + tid;   // 16 frags * 64 lanes = 1024 exact
        int lane = idx & 63, frag = idx >> 6;
        int n = lane & 15;
        unsigned short e[8];
#pragma unroll
        for (int jj = 0; jj < 8; ++jj) {
            int k = frag * 32 + 8 * (lane >> 4) + jj;
            float s = rsqrtf(bn_var[k] + 1e-5f) * bn_gamma[k];
            float v = (n < 10) ? lw[n * 512 + k] * s : (n == 10) ? dw[k] * s : 0.f;
            e[jj] = f2bf(v);
        }
        uint4 pk;
        pk.x = e[0] | ((unsigned)e[1] << 16); pk.y = e[2] | ((unsigned)e[3] << 16);
        pk.z = e[4] | ((unsigned)e[5] << 16); pk.w = e[6] | ((unsigned)e[7] << 16);
        *(uint4*)(hfrag + (size_t)frag * 512 + lane * 8) = pk;
    }
}

// ---------------- conv via MFMA + local cummax + LDS-transpose store -------
// (unchanged from round 6 — passing, conv ≈ sub-65 µs)
__global__ __launch_bounds__(256, 4) void conv_mfma(
    const unsigned short* __restrict__ xT, const unsigned short* __restrict__ Bfrag,
    const float* __restrict__ b1, const float* __restrict__ b2,
    const float* __restrict__ b3, const float* __restrict__ b4,
    unsigned short* __restrict__ feat, unsigned short* __restrict__ totals)
{
    __shared__ __align__(16) unsigned short lds[2688 + 2 * 64 * 132];
    unsigned short* xs = lds;
    unsigned int* stg32 = (unsigned int*)(lds + 2688);   // [64 r2][132 pad] dwords
    const int tid = threadIdx.x;
    const int tq = blockIdx.x & 15;
    const int scale = (blockIdx.x >> 4) & 3;
    const int b = blockIdx.x >> 6;
    const int kh_tab[4] = {5, 10, 15, 20};
    const int so_tab[4] = {0, 40, 120, 240};
    const int KH = kh_tab[scale];
    const int P = 5 * (scale + 1);
    const float* bias = (scale == 0) ? b1 : (scale == 1) ? b2 : (scale == 2) ? b3 : b4;

    const unsigned short* src = xT + ((size_t)b * 2176 + tq * 128) * 16;
#pragma unroll
    for (int it = 0; it < 2; ++it) {
        int c = it * 256 + tid;
        if (c < 336) {
            uint4 v = *(const uint4*)(src + c * 8);
            *(uint4*)((char*)xs + swz(c * 16)) = v;
        }
    }
    __syncthreads();

    const int lane = tid & 63;
    const int wave = tid >> 6;
    const int hgrp = wave & 1;
    const int twq = wave >> 1;
    const int l15 = lane & 15;
    const int g4 = lane >> 4;

    const unsigned short* bfr = Bfrag + ((size_t)(so_tab[scale] + hgrp * 4 * KH)) * 512 + lane * 8;
    float bv[4];
#pragma unroll
    for (int ht = 0; ht < 4; ++ht) bv[ht] = bias[hgrp * 64 + ht * 16 + l15];

    int abase = ((20 - P) + twq * 64 + l15 + (lane >> 5)) * 32 + (g4 & 1) * 16;

    f32x4 acc[4][4];
#pragma unroll
    for (int ht = 0; ht < 4; ++ht)
#pragma unroll
        for (int tt = 0; tt < 4; ++tt)
            acc[ht][tt] = (f32x4){bv[ht], bv[ht], bv[ht], bv[ht]};

#pragma unroll 1
    for (int k0 = 0; k0 < KH; ++k0) {
        bf16x8 B[4], A[4];
#pragma unroll
        for (int ht = 0; ht < 4; ++ht)
            B[ht] = *(const bf16x8*)(bfr + (size_t)(ht * KH + k0) * 512);
#pragma unroll
        for (int tt = 0; tt < 4; ++tt)
            A[tt] = *(const bf16x8*)((const char*)xs + swz(abase + tt * 512 + k0 * 64));
#pragma unroll
        for (int ht = 0; ht < 4; ++ht)
#pragma unroll
            for (int tt = 0; tt < 4; ++tt)
                acc[ht][tt] = __builtin_amdgcn_mfma_f32_16x16x32_bf16(A[tt], B[ht], acc[ht][tt], 0, 0, 0);
    }

    float carry[4] = {NEG_INF, NEG_INF, NEG_INF, NEG_INF};
    const int rq = tq * 2 + twq;
    const int col = hgrp * 64 + l15;

#pragma unroll
    for (int tt = 0; tt < 4; ++tt) {
#pragma unroll
        for (int ht = 0; ht < 4; ++ht) {
            f32x4 v = acc[ht][tt];
            float s0 = v.x;
            float s1 = fmaxf(v.y, s0);
            float s2 = fmaxf(v.z, s1);
            float s3 = fmaxf(v.w, s2);
            float inc = s3;
            float o = __shfl_up(inc, 16); if (lane >= 16) inc = fmaxf(inc, o);
            o = __shfl_up(inc, 32);       if (lane >= 32) inc = fmaxf(inc, o);
            float pre = __shfl_up(inc, 16);
            float base = (lane >= 16) ? fmaxf(carry[ht], pre) : carry[ht];
            s0 = fmaxf(s0, base); s1 = fmaxf(s1, base);
            s2 = fmaxf(s2, base); s3 = fmaxf(s3, base);
            float tot = __shfl(inc, l15 + 48);
            carry[ht] = fmaxf(carry[ht], tot);
            int r2 = twq * 32 + tt * 8 + 2 * g4;
            int cc = col + ht * 16;
            stg32[r2 * 132 + cc]       = pack2(s0, s1);
            stg32[(r2 + 1) * 132 + cc] = pack2(s2, s3);
        }
    }
    if (lane < 16) {
#pragma unroll
        for (int ht = 0; ht < 4; ++ht) {
            int j = scale * 128 + hgrp * 64 + ht * 16 + l15;
            totals[((size_t)b * 32 + rq) * 512 + j] = f2bf(carry[ht]);
        }
    }
    __syncthreads();

    size_t grow = (size_t)b * 2048 + tq * 128;
#pragma unroll
    for (int i = 0; i < 4; ++i) {
        int e = i * 256 + tid;
        int r2 = e >> 4, q = e & 15;
        const unsigned int* p = stg32 + r2 * 132 + q * 8;
        uint4 da = *(const uint4*)(p);
        uint4 db = *(const uint4*)(p + 4);
        uint4 ev, od;
        ev.x = (da.x & 0xffffu) | (da.y << 16);
        ev.y = (da.z & 0xffffu) | (da.w << 16);
        ev.z = (db.x & 0xffffu) | (db.y << 16);
        ev.w = (db.z & 0xffffu) | (db.w << 16);
        od.x = (da.x >> 16) | (da.y & 0xffff0000u);
        od.y = (da.z >> 16) | (da.w & 0xffff0000u);
        od.z = (db.x >> 16) | (db.y & 0xffff0000u);
        od.w = (db.z >> 16) | (db.w & 0xffff0000u);
        size_t base = (grow + 2 * r2) * 512 + scale * 128 + q * 8;
        *(uint4*)(feat + base)       = ev;
        *(uint4*)(feat + base + 512) = od;
    }
}

// ---------------- head via MFMA: M=t, K=512 j, N=16 (10 logits+delta+pad) ---
// grid 1024 = b(32) x tc(32: 64t). block 256 = 4 waves, wave = one 16t tile.
// B-frags (BN-folded, bf16) live in 64 VGPRs; A = fmax(feat, prefix) packed
// exactly (both operands bf16-exact -> truncation, no rounding). Softmax via
// __shfl_xor over the 16-lane n-groups of the C layout.
__global__ __launch_bounds__(256) void head_kernel(
    const unsigned short* __restrict__ feat, const unsigned short* __restrict__ totals,
    const unsigned short* __restrict__ hfrag, const float* __restrict__ bfo,
    const float* __restrict__ dbfo, float* __restrict__ probs,
    float* __restrict__ delta_raw)
{
    __shared__ float pfs[512];
    int b = blockIdx.x >> 5;
    int tc = blockIdx.x & 31;
    int tid = threadIdx.x;
    int lane = tid & 63;
    int wave = tid >> 6;

    // exclusive prefix-max over earlier 64t ranges (coalesced totals reads)
    for (int j = tid; j < 512; j += 256) {
        float run = NEG_INF;
        for (int qq = 0; qq < tc; ++qq)
            run = fmaxf(run, bf2f(totals[((size_t)b * 32 + qq) * 512 + j]));
        pfs[j] = run;
    }
    __syncthreads();

    bf16x8 Bf[16];
#pragma unroll
    for (int k0 = 0; k0 < 16; ++k0)
        Bf[k0] = *(const bf16x8*)(hfrag + (size_t)k0 * 512 + lane * 8);

    const int n = lane & 15;
    const int g4 = lane >> 4;
    const int tb = tc * 64 + wave * 16;
    const unsigned short* fb = feat + ((size_t)b * 2048 + tb + n) * 512 + 8 * g4;

    float biasv = (n < 10) ? bfo[n] : (n == 10) ? dbfo[0] : 0.f;
    f32x4 acc = (f32x4){biasv, biasv, biasv, biasv};

#pragma unroll
    for (int k0 = 0; k0 < 16; ++k0) {
        bf16x8 a = *(const bf16x8*)(fb + k0 * 32);
        const float* pp = pfs + k0 * 32 + 8 * g4;
        union { unsigned int u[4]; bf16x8 v; } aw;
#pragma unroll
        for (int i = 0; i < 4; ++i) {
            float lo = fmaxf(bf2f((unsigned short)a[2 * i]),     pp[2 * i]);
            float hi = fmaxf(bf2f((unsigned short)a[2 * i + 1]), pp[2 * i + 1]);
            // both operands exact bf16 -> result exact bf16 -> truncate-pack
            aw.u[i] = (__float_as_uint(lo) >> 16) | (__float_as_uint(hi) & 0xFFFF0000u);
        }
        acc = __builtin_amdgcn_mfma_f32_16x16x32_bf16(aw.v, Bf[k0], acc, 0, 0, 0);
    }

    // C layout: col n = lane&15, row t = tb + (lane>>4)*4 + r
#pragma unroll
    for (int r = 0; r < 4; ++r) {
        float v = acc[r];
        float vm = (n < 10) ? v : NEG_INF;
#pragma unroll
        for (int off = 1; off < 16; off <<= 1)
            vm = fmaxf(vm, __shfl_xor(vm, off, 16));
        float e = (n < 10) ? __expf(v - vm) : 0.f;
        float s = e;
#pragma unroll
        for (int off = 1; off < 16; off <<= 1)
            s += __shfl_xor(s, off, 16);
        int t = tb + g4 * 4 + r;
        if (n < 10) probs[((size_t)b * 2048 + t) * 10 + n] = e / s;
        if (n == 10) delta_raw[b * 2048 + t] = v;
    }
}

// ---------------- softmax over T + budget chain (wave-shfl scans) ----------
__global__ __launch_bounds__(256) void budget_kernel(
    const float* __restrict__ delta_raw, float* __restrict__ pts)
{
    __shared__ float ds[2048];
    __shared__ float red[8];
    int b = blockIdx.x;
    int tid = threadIdx.x;
    int lane = tid & 63, wid = tid >> 6;
    const float* row = delta_raw + b * 2048;
    int base = tid * 8;
    float d[8];
#pragma unroll
    for (int i = 0; i < 8; ++i) d[i] = row[base + i];
    float m = d[0];
#pragma unroll
    for (int i = 1; i < 8; ++i) m = fmaxf(m, d[i]);
#pragma unroll
    for (int off = 1; off < 64; off <<= 1) m = fmaxf(m, __shfl_xor(m, off));
    if (lane == 0) red[wid] = m;
    __syncthreads();
    m = fmaxf(fmaxf(red[0], red[1]), fmaxf(red[2], red[3]));
    float s = 0.f;
#pragma unroll
    for (int i = 0; i < 8; ++i) { d[i] = __expf(d[i] - m); s += d[i]; }
#pragma unroll
    for (int off = 1; off < 64; off <<= 1) s += __shfl_xor(s, off);
    if (lane == 0) red[4 + wid] = s;
    __syncthreads();
    float inv = 1.f / (red[4] + red[5] + red[6] + red[7]);
    float g[8], p = 1.f;
#pragma unroll
    for (int i = 0; i < 8; ++i) {
        d[i] *= inv;
        ds[base + i] = d[i];
        float gv = (base + i == 0) ? 1.f : (1.f - d[i]);
        p *= gv;
        g[i] = p;                      // inclusive within thread
    }
    float sp = p;
#pragma unroll
    for (int off = 1; off < 64; off <<= 1) {
        float o = __shfl_up(sp, off);
        if (lane >= off) sp *= o;
    }
    float pre_t = __shfl_up(sp, 1);
    if (lane == 0) pre_t = 1.f;
    if (lane == 63) red[wid] = sp;     // wave totals (red[0..3] free post-read)
    __syncthreads();
    float wpre = 1.f;
#pragma unroll
    for (int w = 0; w < 4; ++w) if (w < wid) wpre *= red[w];
    float pre = wpre * pre_t;          // exclusive prefix product of q up to base
#pragma unroll
    for (int i = 0; i < 8; ++i) {
        int t = base + i;
        float budget = pre * g[i];     // = prod_{1<=s<=t}(1-d_s)
        float pt = (t < 2047) ? ds[t + 1] * budget : budget;
        pts[b * 2048 + t] = pt;
    }
}

extern "C" void kernel_launch(void* const* d_in, const int* in_sizes, int n_in,
                              void* d_out, int out_size, void* d_ws, size_t ws_size,
                              hipStream_t stream)
{
    const float* x     = (const float*)d_in[0];
    const float* w1    = (const float*)d_in[1];
    const float* b1    = (const float*)d_in[2];
    const float* w2    = (const float*)d_in[3];
    const float* b2    = (const float*)d_in[4];
    const float* w3    = (const float*)d_in[5];
    const float* b3    = (const float*)d_in[6];
    const float* w4    = (const float*)d_in[7];
    const float* b4    = (const float*)d_in[8];
    const float* gamma = (const float*)d_in[9];
    const float* beta  = (const float*)d_in[10];
    const float* mean  = (const float*)d_in[11];
    const float* var   = (const float*)d_in[12];
    const float* lw    = (const float*)d_in[13];
    const float* lb    = (const float*)d_in[14];
    const float* dw    = (const float*)d_in[15];
    const float* db    = (const float*)d_in[16];

    char* ws = (char*)d_ws;
    unsigned short* feat   = (unsigned short*)ws;                 // 67,108,864 B
    unsigned short* xT     = (unsigned short*)(ws + 67108864);    //  2,228,224 B
    unsigned short* Bfrag  = (unsigned short*)(ws + 69337088);    //    409,600 B
    unsigned short* totals = (unsigned short*)(ws + 69746688);    //  1,048,576 B
    float* draw   = (float*)(ws + 70795264);                      //    262,144 B
    unsigned short* hfrag = (unsigned short*)(ws + 71057408);     //     16,384 B
    float* bfo    = (float*)(ws + 71073792);                      //         64 B
    float* dbfo   = (float*)(ws + 71073856);                      //         64 B
    // total ws use: 71,073,920 B (<= proven footprint)

    float* probs = (float*)d_out;
    float* pts   = probs + (size_t)32 * 2048 * 10;

    hipLaunchKernelGGL(prep_kernel, dim3(189), dim3(512), 0, stream,
                       x, w1, w2, w3, w4, gamma, beta, mean, var,
                       lw, lb, dw, db, xT, Bfrag, hfrag, bfo, dbfo);
    hipLaunchKernelGGL(conv_mfma, dim3(2048), dim3(256), 0, stream,
                       xT, Bfrag, b1, b2, b3, b4, feat, totals);
    hipLaunchKernelGGL(head_kernel, dim3(1024), dim3(256), 0, stream,
                       feat, totals, hfrag, bfo, dbfo, probs, draw);
    hipLaunchKernelGGL(budget_kernel, dim3(32), dim3(256), 0, stream, draw, pts);
}